// Round 21
// baseline (1297.192 us; speedup 1.0000x reference)
//
#include <hip/hip_runtime.h>
#include <cstdint>
#include <cstddef>

// ---------------- constants ----------------
#define NN 10000
#define EE 160000
#define F_IN 128
#define HH 64
#define HEADS 8
#define LL 6
#define MM 512
#define OUT_DIM 64
#define EPSF 1e-5f

typedef unsigned short ushort;
typedef unsigned char uchar;
typedef __attribute__((ext_vector_type(8))) short bf16x8;
typedef __attribute__((ext_vector_type(8))) unsigned short ushort8;
typedef __attribute__((ext_vector_type(4))) float f32x4;

union U8 { ushort8 u; bf16x8 b; };

// ---------------- threefry (JAX-compatible) ----------------
struct U2 { uint32_t a, b; };

__host__ __device__ constexpr uint32_t rotl32(uint32_t x, uint32_t d) {
  return (x << d) | (x >> (32u - d));
}

__host__ __device__ constexpr U2 threefry2x32(uint32_t k1, uint32_t k2, uint32_t x0, uint32_t x1) {
  uint32_t ks2 = k1 ^ k2 ^ 0x1BD11BDAu;
  x0 += k1; x1 += k2;
  x0 += x1; x1 = rotl32(x1, 13); x1 ^= x0;
  x0 += x1; x1 = rotl32(x1, 15); x1 ^= x0;
  x0 += x1; x1 = rotl32(x1, 26); x1 ^= x0;
  x0 += x1; x1 = rotl32(x1, 6);  x1 ^= x0;
  x0 += k2; x1 += ks2 + 1u;
  x0 += x1; x1 = rotl32(x1, 17); x1 ^= x0;
  x0 += x1; x1 = rotl32(x1, 29); x1 ^= x0;
  x0 += x1; x1 = rotl32(x1, 16); x1 ^= x0;
  x0 += x1; x1 = rotl32(x1, 24); x1 ^= x0;
  x0 += ks2; x1 += k1 + 2u;
  x0 += x1; x1 = rotl32(x1, 13); x1 ^= x0;
  x0 += x1; x1 = rotl32(x1, 15); x1 ^= x0;
  x0 += x1; x1 = rotl32(x1, 26); x1 ^= x0;
  x0 += x1; x1 = rotl32(x1, 6);  x1 ^= x0;
  x0 += k1; x1 += k2 + 3u;
  x0 += x1; x1 = rotl32(x1, 17); x1 ^= x0;
  x0 += x1; x1 = rotl32(x1, 29); x1 ^= x0;
  x0 += x1; x1 = rotl32(x1, 16); x1 ^= x0;
  x0 += x1; x1 = rotl32(x1, 24); x1 ^= x0;
  x0 += k2; x1 += ks2 + 4u;
  x0 += x1; x1 = rotl32(x1, 13); x1 ^= x0;
  x0 += x1; x1 = rotl32(x1, 15); x1 ^= x0;
  x0 += x1; x1 = rotl32(x1, 26); x1 ^= x0;
  x0 += x1; x1 = rotl32(x1, 6);  x1 ^= x0;
  x0 += ks2; x1 += k1 + 5u;
  return U2{x0, x1};
}

__host__ __device__ constexpr U2 foldKey(uint32_t data) {
  return threefry2x32(0u, 42u, 0u, data);
}

// XLA ErfInv f32 (Giles)
__device__ inline float erfinv_f32(float x) {
  float w = -log1pf(-x * x);
  float p;
  if (w < 5.0f) {
    w -= 2.5f;
    p = 2.81022636e-08f;
    p = fmaf(p, w, 3.43273939e-07f);
    p = fmaf(p, w, -3.5233877e-06f);
    p = fmaf(p, w, -4.39150654e-06f);
    p = fmaf(p, w, 0.00021858087f);
    p = fmaf(p, w, -0.00125372503f);
    p = fmaf(p, w, -0.00417768164f);
    p = fmaf(p, w, 0.246640727f);
    p = fmaf(p, w, 1.50140941f);
  } else {
    w = sqrtf(w) - 3.0f;
    p = -0.000200214257f;
    p = fmaf(p, w, 0.000100950558f);
    p = fmaf(p, w, 0.00134934322f);
    p = fmaf(p, w, -0.00367342844f);
    p = fmaf(p, w, 0.00573950773f);
    p = fmaf(p, w, -0.0076224613f);
    p = fmaf(p, w, 0.00943887047f);
    p = fmaf(p, w, 1.00167406f);
    p = fmaf(p, w, 2.83297682f);
  }
  return p * x;
}

__device__ inline float jax_normal(uint32_t k1, uint32_t k2, uint32_t idx) {
  U2 r = threefry2x32(k1, k2, 0u, idx);
  uint32_t bits = r.a ^ r.b;
  uint32_t fb = (bits >> 9) | 0x3f800000u;
  float f = __uint_as_float(fb) - 1.0f;
  const float lo = -0.99999994f;
  float u = f * 2.0f + lo;
  u = fmaxf(lo, u);
  return 1.41421356f * erfinv_f32(u);
}

// ---------------- helpers ----------------
__device__ inline float waveSum(float v) {
  v += __shfl_xor(v, 32, 64);
  v += __shfl_xor(v, 16, 64);
  v += __shfl_xor(v, 8, 64);
  v += __shfl_xor(v, 4, 64);
  v += __shfl_xor(v, 2, 64);
  v += __shfl_xor(v, 1, 64);
  return v;
}
__device__ inline float waveMax(float v) {
  v = fmaxf(v, __shfl_xor(v, 32, 64));
  v = fmaxf(v, __shfl_xor(v, 16, 64));
  v = fmaxf(v, __shfl_xor(v, 8, 64));
  v = fmaxf(v, __shfl_xor(v, 4, 64));
  v = fmaxf(v, __shfl_xor(v, 2, 64));
  v = fmaxf(v, __shfl_xor(v, 1, 64));
  return v;
}

__device__ inline ushort bf16rn(float x) {
  uint32_t u = __float_as_uint(x);
  uint32_t r = (u + 0x7fffu + ((u >> 16) & 1u)) >> 16;
  return (ushort)r;
}
__device__ inline float bf16tof(ushort h) {
  return __uint_as_float(((uint32_t)h) << 16);
}

// ---------------- kernels ----------------

// encoder: h = relu(LN(x @ W + b; g,be)) + cm*0.1  -> h f32 + bf16 hi/lo planes; zeroes resid
__global__ __launch_bounds__(64) void encoder_kernel(
    const float* __restrict__ x, const float* __restrict__ W, const float* __restrict__ b,
    const float* __restrict__ g, const float* __restrict__ be, const float* __restrict__ cm,
    float* __restrict__ h, ushort* __restrict__ hHi, ushort* __restrict__ hLo,
    float* __restrict__ resid) {
  __shared__ float xs[F_IN];
  int n = blockIdx.x, l = threadIdx.x;
  xs[l]      = x[(size_t)n * F_IN + l];
  xs[l + 64] = x[(size_t)n * F_IN + 64 + l];
  resid[(size_t)n * HH + l] = 0.0f;   // fused resid zero-init (was a separate memset)
  __syncthreads();
  float acc = b[l];
  #pragma unroll 8
  for (int k = 0; k < F_IN; k++) acc = fmaf(xs[k], W[k * HH + l], acc);
  float mu = waveSum(acc) * (1.0f / 64.0f);
  float d = acc - mu;
  float var = waveSum(d * d) * (1.0f / 64.0f);
  float y = fmaf(d / sqrtf(var + EPSF), g[l], be[l]);
  y = fmaxf(y, 0.0f);
  float hv = fmaf(cm[l], 0.1f, y);
  h[(size_t)n * HH + l] = hv;
  ushort hi = bf16rn(hv);
  size_t oi = ((size_t)(l >> 5) * NN + n) * 32 + (l & 31);
  hHi[oi] = hi;
  hLo[oi] = bf16rn(hv - bf16tof(hi));
}

// weight convert+transpose: W[K][512] f32 -> [K/32][512][32] bf16 hi/lo, per layer (z)
__global__ __launch_bounds__(256) void wconv(
    const float* __restrict__ W, ushort* __restrict__ oh, ushort* __restrict__ ol, int K) {
  __shared__ ushort Th[64][40], Tl[64][40];
  int kt = blockIdx.x;
  int m0 = blockIdx.y * 64;
  int lay = blockIdx.z;
  const float* Wl = W + (size_t)lay * K * MM;
  ushort* ohl = oh + (size_t)lay * K * MM;
  ushort* oll = ol + (size_t)lay * K * MM;
  int t = threadIdx.x;
  #pragma unroll
  for (int p = 0; p < 2; ++p) {
    int li = p * 256 + t;
    int k = li >> 4, mg = (li & 15) * 4;
    float4 v = *(const float4*)(Wl + (size_t)(kt * 32 + k) * MM + m0 + mg);
    float vv[4] = {v.x, v.y, v.z, v.w};
    #pragma unroll
    for (int q = 0; q < 4; ++q) {
      ushort hi = bf16rn(vv[q]);
      Th[mg + q][k] = hi;
      Tl[mg + q][k] = bf16rn(vv[q] - bf16tof(hi));
    }
  }
  __syncthreads();
  #pragma unroll
  for (int p = 0; p < 2; ++p) {
    int li = p * 256 + t;
    int plane = li >> 8;
    int rem = li & 255;
    int m = rem >> 2, kh = (rem & 3) * 8;
    size_t go = ((size_t)kt * MM + m0 + m) * 32 + kh;
    if (plane == 0) *(ushort8*)(ohl + go) = *(const ushort8*)&Th[m][kh];
    else            *(ushort8*)(oll + go) = *(const ushort8*)&Tl[m][kh];
  }
}

// ---- GEMM: C[NN,512] (bf16) = A @ W + bias. 128x64 tile, 256 thr, LDS-staged A and B.
// XCD-row-partitioned grid (R15-verified). ----
__global__ __launch_bounds__(256) void gemm_mfma(
    const ushort* __restrict__ Ahg, const ushort* __restrict__ Alg,
    const ushort* __restrict__ Whg, const ushort* __restrict__ Wlg,
    const float* __restrict__ bias, ushort* __restrict__ C, int nkt) {
  __shared__ __align__(16) ushort Ah[128][36], Al[128][36];
  __shared__ __align__(16) ushort Bh[64][36],  Bl[64][36];
  int t = threadIdx.x, w = t >> 6, lane = t & 63;
  int lr = lane & 15, r4 = lane >> 4, kh = r4 * 8;
  int gid = blockIdx.x;
  int xcd = gid & 7, q = gid >> 3;
  int lrow = q >> 3, colp = q & 7;
  int rowTile = xcd * 10 + lrow;
  if (rowTile >= 79) return;
  int row0 = rowTile * 128, col0 = colp * 64;
  int wr = (w & 1) * 64, wc = (w >> 1) * 32;
  f32x4 acc[4][2];
  #pragma unroll
  for (int i = 0; i < 4; i++)
    #pragma unroll
    for (int j = 0; j < 2; j++) acc[i][j] = (f32x4){0.f, 0.f, 0.f, 0.f};

  for (int kt = 0; kt < nkt; ++kt) {
    #pragma unroll
    for (int p = 0; p < 2; ++p) {
      int li = p * 256 + t;
      int r = li >> 2, kq = (li & 3) * 8;
      int n = row0 + r;
      ushort8 va = {0,0,0,0,0,0,0,0}, vl = {0,0,0,0,0,0,0,0};
      if (n < NN) {
        size_t so = ((size_t)kt * NN + n) * 32 + kq;
        va = *(const ushort8*)(Ahg + so);
        vl = *(const ushort8*)(Alg + so);
      }
      *(ushort8*)&Ah[r][kq] = va;
      *(ushort8*)&Al[r][kq] = vl;
    }
    {
      int c = t >> 2, kq = (t & 3) * 8;
      size_t so = ((size_t)kt * MM + col0 + c) * 32 + kq;
      *(ushort8*)&Bh[c][kq] = *(const ushort8*)(Whg + so);
      *(ushort8*)&Bl[c][kq] = *(const ushort8*)(Wlg + so);
    }
    __syncthreads();
    bf16x8 bh[2], bl[2];
    #pragma unroll
    for (int cf = 0; cf < 2; ++cf) {
      bh[cf] = *(const bf16x8*)&Bh[wc + cf * 16 + lr][kh];
      bl[cf] = *(const bf16x8*)&Bl[wc + cf * 16 + lr][kh];
    }
    #pragma unroll
    for (int rf = 0; rf < 4; ++rf) {
      bf16x8 ah = *(const bf16x8*)&Ah[wr + rf * 16 + lr][kh];
      bf16x8 al = *(const bf16x8*)&Al[wr + rf * 16 + lr][kh];
      #pragma unroll
      for (int cf = 0; cf < 2; ++cf) {
        acc[rf][cf] = __builtin_amdgcn_mfma_f32_16x16x32_bf16(ah, bh[cf], acc[rf][cf], 0, 0, 0);
        acc[rf][cf] = __builtin_amdgcn_mfma_f32_16x16x32_bf16(ah, bl[cf], acc[rf][cf], 0, 0, 0);
        acc[rf][cf] = __builtin_amdgcn_mfma_f32_16x16x32_bf16(al, bh[cf], acc[rf][cf], 0, 0, 0);
      }
    }
    __syncthreads();
  }
  #pragma unroll
  for (int cf = 0; cf < 2; ++cf) {
    int c = col0 + wc + cf * 16 + lr;
    float bc = bias[c];
    #pragma unroll
    for (int rf = 0; rf < 4; ++rf) {
      #pragma unroll
      for (int j = 0; j < 4; ++j) {
        int r = row0 + wr + rf * 16 + r4 * 4 + j;
        if (r < NN) C[(size_t)r * MM + c] = bf16rn(acc[rf][cf][j] + bc);
      }
    }
  }
}

// LN+relu (+feats accum, bf16) (+acts+noise pack) (+stage2: int8 featsPk + scales + GAT scores)
__global__ __launch_bounds__(256) void ln_relu_acc(
    const ushort* __restrict__ Y, const float* __restrict__ g, const float* __restrict__ be,
    ushort* __restrict__ feats, int firstDepth,
    ushort* __restrict__ outHi, ushort* __restrict__ outLo,
    uint32_t k1, uint32_t k2, float cf,
    const float* __restrict__ attL, float* __restrict__ ai, float* __restrict__ aj,
    uchar* __restrict__ featsPk8, float* __restrict__ scales) {
  int n = blockIdx.x, t = threadIdx.x;
  size_t base = (size_t)n * MM;
  float v0 = bf16tof(Y[base + t]), v1 = bf16tof(Y[base + t + 256]);
  int wid = t >> 6, lane = t & 63;
  __shared__ float red[8];
  __shared__ uchar qsh[512];
  float s = waveSum(v0 + v1);
  if (lane == 0) red[wid] = s;
  __syncthreads();
  float mu = (red[0] + red[1] + red[2] + red[3]) * (1.0f / 512.0f);
  float d0 = v0 - mu, d1 = v1 - mu;
  float q = waveSum(d0 * d0 + d1 * d1);
  if (lane == 0) red[4 + wid] = q;
  __syncthreads();
  float var = (red[4] + red[5] + red[6] + red[7]) * (1.0f / 512.0f);
  float inv = 1.0f / sqrtf(var + EPSF);
  float o0 = fmaxf(fmaf(d0 * inv, g[t], be[t]), 0.0f);
  float o1 = fmaxf(fmaf(d1 * inv, g[t + 256], be[t + 256]), 0.0f);
  float f0, f1;
  if (firstDepth) { f0 = o0; f1 = o1; }
  else { f0 = bf16tof(feats[base + t]) + o0; f1 = bf16tof(feats[base + t + 256]) + o1; }
  if (outHi) {
    feats[base + t] = bf16rn(f0); feats[base + t + 256] = bf16rn(f1);
    float y0 = fmaf(jax_normal(k1, k2, (uint32_t)(base + t)), cf, o0);
    float y1 = fmaf(jax_normal(k1, k2, (uint32_t)(base + t + 256)), cf, o1);
    int c0 = t, c1 = t + 256;
    size_t i0 = ((size_t)(c0 >> 5) * NN + n) * 32 + (c0 & 31);
    size_t i1 = ((size_t)(c1 >> 5) * NN + n) * 32 + (c1 & 31);
    ushort h0 = bf16rn(y0), h1 = bf16rn(y1);
    outHi[i0] = h0; outLo[i0] = bf16rn(y0 - bf16tof(h0));
    outHi[i1] = h1; outLo[i1] = bf16rn(y1 - bf16tof(h1));
  }
  if (attL) {
    const float inv3 = 1.0f / 3.0f;
    float w0 = f0 * inv3, w1 = f1 * inv3;
    float si0 = waveSum(w0 * attL[wid * 128 + lane]);
    float sj0 = waveSum(w0 * attL[wid * 128 + 64 + lane]);
    float si1 = waveSum(w1 * attL[(wid + 4) * 128 + lane]);
    float sj1 = waveSum(w1 * attL[(wid + 4) * 128 + 64 + lane]);
    float mx0 = waveMax(w0), mx1 = waveMax(w1);
    float r0 = (mx0 > 0.f) ? (127.0f / mx0) : 0.f;
    float r1 = (mx1 > 0.f) ? (127.0f / mx1) : 0.f;
    if (lane == 0) {
      ai[n * HEADS + wid] = si0;     aj[n * HEADS + wid] = sj0;
      ai[n * HEADS + wid + 4] = si1; aj[n * HEADS + wid + 4] = sj1;
      scales[n * HEADS + wid]     = (mx0 > 0.f) ? (mx0 * (1.0f / 127.0f)) : 0.f;
      scales[n * HEADS + wid + 4] = (mx1 > 0.f) ? (mx1 * (1.0f / 127.0f)) : 0.f;
    }
    int q0 = min(127, (int)rintf(w0 * r0));
    int q1 = min(127, (int)rintf(w1 * r1));
    qsh[lane * 8 + wid]     = (uchar)q0;
    qsh[lane * 8 + wid + 4] = (uchar)q1;
    __syncthreads();
    if (t < 32) ((uint4*)(featsPk8 + (size_t)n * 512))[t] = ((const uint4*)qsh)[t];
  }
}

// -------- CSR build --------
__global__ __launch_bounds__(256) void csr_histo(const int* __restrict__ dst, int* __restrict__ deg) {
  int e = blockIdx.x * blockDim.x + threadIdx.x;
  if (e < EE) atomicAdd(&deg[dst[e]], 1);
}

// scan also seeds pos[] (deletes the old D2D memcpy dispatch)
__global__ __launch_bounds__(256) void csr_scan(const int* __restrict__ deg, int* __restrict__ offs,
                                                int* __restrict__ pos) {
  __shared__ int part[256];
  int t = threadIdx.x;
  const int chunk = (NN + 255) / 256;
  int start = t * chunk;
  int s = 0;
  for (int j = 0; j < chunk; j++) { int i = start + j; if (i < NN) s += deg[i]; }
  part[t] = s; __syncthreads();
  for (int d = 1; d < 256; d <<= 1) {
    int v = (t >= d) ? part[t - d] : 0;
    __syncthreads();
    part[t] += v;
    __syncthreads();
  }
  int run = (t == 0) ? 0 : part[t - 1];
  for (int j = 0; j < chunk; j++) {
    int i = start + j;
    if (i < NN) { offs[i] = run; pos[i] = run; run += deg[i]; }
  }
  if (t == 0) offs[NN] = EE;
}

__global__ __launch_bounds__(256) void csr_fill(const int* __restrict__ src, const int* __restrict__ dst,
                                                int* __restrict__ pos, int* __restrict__ csrc) {
  int e = blockIdx.x * blockDim.x + threadIdx.x;
  if (e >= EE) return;
  int d = dst[e];
  int slot = atomicAdd(&pos[d], 1);
  csrc[slot] = src[e];
}

// -------- fused GAT v5.1: wave-per-node, zero barriers, int8 ch-major gather, 4-deep uint2 batch --------
__global__ __launch_bounds__(256) void gat_fused(
    const int* __restrict__ offs, const int* __restrict__ csrc,
    const float* __restrict__ ai, const float* __restrict__ aj,
    const uchar* __restrict__ featsPk8, const float* __restrict__ scales,
    const float* __restrict__ W1, const float* __restrict__ b1,
    const float* __restrict__ W2, const float* __restrict__ b2,
    float* __restrict__ h, float* __restrict__ resid,
    ushort* __restrict__ hHi, ushort* __restrict__ hLo) {
  __shared__ int   sSrc[4][64];
  __shared__ float sEx[4][8][64];   // ex * scale[src][h]
  __shared__ float hnSh[4][64];
  __shared__ float zSh[4][128];
  int t = threadIdx.x, wid = t >> 6, l = t & 63;
  int n = blockIdx.x * 4 + wid;            // NN = 2500*4 exactly
  int e0 = offs[n], e1 = offs[n + 1];
  float aiv[8];
  *(float4*)&aiv[0] = *(const float4*)&ai[(size_t)n * 8];
  *(float4*)&aiv[4] = *(const float4*)&ai[(size_t)n * 8 + 4];
  float m[8];
  #pragma unroll
  for (int q = 0; q < 8; ++q) m[q] = aiv[q] + 4.0f;

  float exAcc[8] = {0.f, 0.f, 0.f, 0.f, 0.f, 0.f, 0.f, 0.f};
  float acc[8]   = {0.f, 0.f, 0.f, 0.f, 0.f, 0.f, 0.f, 0.f};

  for (int c = e0; c < e1; c += 64) {
    int cnt = min(64, e1 - c);
    // phase A: lane j stages edge c+j (same-wave LDS, no barrier)
    if (l < cnt) {
      int sv = csrc[c + l];
      sSrc[wid][l] = sv;
      float ajv[8], sc[8];
      *(float4*)&ajv[0] = *(const float4*)&aj[(size_t)sv * 8];
      *(float4*)&ajv[4] = *(const float4*)&aj[(size_t)sv * 8 + 4];
      *(float4*)&sc[0]  = *(const float4*)&scales[(size_t)sv * 8];
      *(float4*)&sc[4]  = *(const float4*)&scales[(size_t)sv * 8 + 4];
      #pragma unroll
      for (int q = 0; q < 8; ++q) {
        float a = aiv[q] + ajv[q];
        a = (a >= 0.f) ? a : 0.2f * a;
        float ex = expf(a - m[q]);
        exAcc[q] += ex;
        sEx[wid][q][l] = ex * sc[q];
      }
    }
    // phase B: 4-deep batched uint2 gathers
    int j = 0;
    for (; j + 4 <= cnt; j += 4) {
      uint2 v0 = *(const uint2*)(featsPk8 + (size_t)sSrc[wid][j + 0] * 512 + l * 8);
      uint2 v1 = *(const uint2*)(featsPk8 + (size_t)sSrc[wid][j + 1] * 512 + l * 8);
      uint2 v2 = *(const uint2*)(featsPk8 + (size_t)sSrc[wid][j + 2] * 512 + l * 8);
      uint2 v3 = *(const uint2*)(featsPk8 + (size_t)sSrc[wid][j + 3] * 512 + l * 8);
      #pragma unroll
      for (int b = 0; b < 4; ++b) {
        uint2 v = (b == 0) ? v0 : (b == 1) ? v1 : (b == 2) ? v2 : v3;
        int jb = j + b;
        acc[0] = fmaf((float)( v.x        & 0xffu), sEx[wid][0][jb], acc[0]);
        acc[1] = fmaf((float)((v.x >>  8) & 0xffu), sEx[wid][1][jb], acc[1]);
        acc[2] = fmaf((float)((v.x >> 16) & 0xffu), sEx[wid][2][jb], acc[2]);
        acc[3] = fmaf((float)( v.x >> 24         ), sEx[wid][3][jb], acc[3]);
        acc[4] = fmaf((float)( v.y        & 0xffu), sEx[wid][4][jb], acc[4]);
        acc[5] = fmaf((float)((v.y >>  8) & 0xffu), sEx[wid][5][jb], acc[5]);
        acc[6] = fmaf((float)((v.y >> 16) & 0xffu), sEx[wid][6][jb], acc[6]);
        acc[7] = fmaf((float)( v.y >> 24         ), sEx[wid][7][jb], acc[7]);
      }
    }
    for (; j < cnt; ++j) {
      uint2 v = *(const uint2*)(featsPk8 + (size_t)sSrc[wid][j] * 512 + l * 8);
      acc[0] = fmaf((float)( v.x        & 0xffu), sEx[wid][0][j], acc[0]);
      acc[1] = fmaf((float)((v.x >>  8) & 0xffu), sEx[wid][1][j], acc[1]);
      acc[2] = fmaf((float)((v.x >> 16) & 0xffu), sEx[wid][2][j], acc[2]);
      acc[3] = fmaf((float)( v.x >> 24         ), sEx[wid][3][j], acc[3]);
      acc[4] = fmaf((float)( v.y        & 0xffu), sEx[wid][4][j], acc[4]);
      acc[5] = fmaf((float)((v.y >>  8) & 0xffu), sEx[wid][5][j], acc[5]);
      acc[6] = fmaf((float)((v.y >> 16) & 0xffu), sEx[wid][6][j], acc[6]);
      acc[7] = fmaf((float)( v.y >> 24         ), sEx[wid][7][j], acc[7]);
    }
  }
  // denominators (per head, wave-wide) and lane-local head mean (ch = l)
  float hsum = 0.f;
  #pragma unroll
  for (int q = 0; q < 8; ++q) {
    float d = waveSum(exAcc[q]);
    hsum += acc[q] * ((d > 0.f) ? (1.0f / d) : 0.f);
  }
  hnSh[wid][l] = hsum * 0.125f;
  // gate MLP (wave-private)
  float zz0 = b1[l], zz1 = b1[l + 64];
  #pragma unroll 8
  for (int k = 0; k < 64; k++) {
    float hv = hnSh[wid][k];
    zz0 = fmaf(hv, W1[k * 128 + l], zz0);
    zz1 = fmaf(hv, W1[k * 128 + 64 + l], zz1);
  }
  zSh[wid][l] = fmaxf(zz0, 0.f);
  zSh[wid][l + 64] = fmaxf(zz1, 0.f);
  float y = b2[l];
  #pragma unroll 8
  for (int k = 0; k < 128; k++) y = fmaf(zSh[wid][k], W2[k * 64 + l], y);
  float gate = 1.0f / (1.0f + expf(-tanhf(y)));
  float hp = h[(size_t)n * HH + l];
  float hb = gate * hnSh[wid][l] + (1.0f - gate) * hp;
  resid[(size_t)n * HH + l] += hb;
  float mu = waveSum(hb) * (1.0f / 64.0f);
  float dd = hb - mu;
  float var = waveSum(dd * dd) * (1.0f / 64.0f);
  float hv = dd / sqrtf(var + EPSF);
  h[(size_t)n * HH + l] = hv;
  ushort hi = bf16rn(hv);
  size_t oi = ((size_t)(l >> 5) * NN + n) * 32 + (l & 31);
  hHi[oi] = hi;
  hLo[oi] = bf16rn(hv - bf16tof(hi));
}

// decoders; out layout: state[N], imp[N], chaos[N], evo[N*64], h_multi[N*64]
__global__ __launch_bounds__(64) void decoder_kernel(
    const float* __restrict__ resid,
    const float* __restrict__ dsW, const float* __restrict__ dsb,
    const float* __restrict__ diW, const float* __restrict__ dib,
    const float* __restrict__ dcW, const float* __restrict__ dcb,
    const float* __restrict__ deW, const float* __restrict__ deb,
    float* __restrict__ out) {
  __shared__ float hm[64];
  int n = blockIdx.x, l = threadIdx.x;
  float v = resid[(size_t)n * HH + l] * (1.0f / 6.0f);
  hm[l] = v;
  float s1 = waveSum(v * dsW[l]);
  float s2 = waveSum(v * diW[l]);
  float s3 = waveSum(v * dcW[l]);
  if (l == 0) {
    out[n]          = s1 + dsb[0];
    out[NN + n]     = s2 + dib[0];
    out[2 * NN + n] = s3 + dcb[0];
  }
  __syncthreads();
  float e = deb[l];
  #pragma unroll 8
  for (int k = 0; k < 64; k++) e = fmaf(hm[k], deW[k * OUT_DIM + l], e);
  out[3 * NN + (size_t)n * OUT_DIM + l] = e;
  out[3 * NN + (size_t)NN * OUT_DIM + (size_t)n * HH + l] = v;
}

// ---------------- launch ----------------
extern "C" void kernel_launch(void* const* d_in, const int* in_sizes, int n_in,
                              void* d_out, int out_size, void* d_ws, size_t ws_size,
                              hipStream_t stream) {
  const float* x        = (const float*)d_in[0];
  const int*   ei       = (const int*)d_in[1];
  const float* enc_W    = (const float*)d_in[2];
  const float* enc_b    = (const float*)d_in[3];
  const float* enc_g    = (const float*)d_in[4];
  const float* enc_beta = (const float*)d_in[5];
  const float* cm       = (const float*)d_in[6];
  const float* tW0 = (const float*)d_in[7];  const float* tb0 = (const float*)d_in[8];
  const float* tg0 = (const float*)d_in[9];  const float* tbe0 = (const float*)d_in[10];
  const float* tW1 = (const float*)d_in[11]; const float* tb1 = (const float*)d_in[12];
  const float* tg1 = (const float*)d_in[13]; const float* tbe1 = (const float*)d_in[14];
  const float* tW2 = (const float*)d_in[15]; const float* tb2 = (const float*)d_in[16];
  const float* tg2 = (const float*)d_in[17]; const float* tbe2 = (const float*)d_in[18];
  const float* att = (const float*)d_in[19];
  const float* evo_W1 = (const float*)d_in[20]; const float* evo_b1 = (const float*)d_in[21];
  const float* evo_W2 = (const float*)d_in[22]; const float* evo_b2 = (const float*)d_in[23];
  const float* dsW = (const float*)d_in[24]; const float* dsb = (const float*)d_in[25];
  const float* diW = (const float*)d_in[26]; const float* dib = (const float*)d_in[27];
  const float* dcW = (const float*)d_in[28]; const float* dcb = (const float*)d_in[29];
  const float* deW = (const float*)d_in[30]; const float* deb = (const float*)d_in[31];
  float* out = (float*)d_out;

  const int* src = ei;
  const int* dst = ei + EE;

  float* ws = (float*)d_ws;
  size_t o = 0;
  float* h     = ws + o; o += (size_t)NN * HH;
  float* resid = ws + o; o += (size_t)NN * HH;
  float* ai    = ws + o; o += (size_t)NN * HEADS;
  float* aj    = ws + o; o += (size_t)NN * HEADS;
  float* scales = ws + o; o += (size_t)NN * HEADS;
  int* deg  = (int*)(ws + o); o += NN;
  int* offs = (int*)(ws + o); o += NN + 2;
  int* pos  = (int*)(ws + o); o += NN;
  int* csrc = (int*)(ws + o); o += EE;
  o = (o + 3) & ~(size_t)3;  // 16B align
  uchar* featsPk8 = (uchar*)(ws + o); o += (size_t)NN * 128;  // N*512 bytes
  ushort* us = (ushort*)(ws + o);
  size_t uo = 0;
  ushort* W0h = us + uo; uo += (size_t)LL * HH * MM;
  ushort* W0l = us + uo; uo += (size_t)LL * HH * MM;
  ushort* W1h = us + uo; uo += (size_t)LL * MM * MM;
  ushort* W1l = us + uo; uo += (size_t)LL * MM * MM;
  ushort* W2h = us + uo; uo += (size_t)LL * MM * MM;
  ushort* W2l = us + uo; uo += (size_t)LL * MM * MM;
  ushort* hHi = us + uo; uo += (size_t)NN * HH;
  ushort* hLo = us + uo; uo += (size_t)NN * HH;
  ushort* actHi = us + uo; uo += (size_t)NN * MM;
  ushort* actLo = us + uo; uo += (size_t)NN * MM;
  ushort* Cbuf  = us + uo; uo += (size_t)NN * MM;   // bf16 GEMM output
  ushort* feats = us + uo; uo += (size_t)NN * MM;   // bf16 feats accumulator
  (void)ws_size; (void)n_in; (void)in_sizes; (void)out_size;

  // weight conversion (deterministic each call)
  wconv<<<dim3(2, 8, 6), 256, 0, stream>>>(tW0, W0h, W0l, HH);
  wconv<<<dim3(16, 8, 6), 256, 0, stream>>>(tW1, W1h, W1l, MM);
  wconv<<<dim3(16, 8, 6), 256, 0, stream>>>(tW2, W2h, W2l, MM);

  // CSR build (csr_scan also seeds pos; no D2D memcpy)
  hipMemsetAsync(deg, 0, (size_t)NN * sizeof(int), stream);
  csr_histo<<<(EE + 255) / 256, 256, 0, stream>>>(dst, deg);
  csr_scan<<<1, 256, 0, stream>>>(deg, offs, pos);
  csr_fill<<<(EE + 255) / 256, 256, 0, stream>>>(src, dst, pos, csrc);

  encoder_kernel<<<NN, 64, 0, stream>>>(x, enc_W, enc_b, enc_g, enc_beta, cm, h, hHi, hLo, resid);

  const int GEMM_GRID = 640;  // 8 XCDs x 10 row-tiles x 8 col-panels (row-partitioned)
  for (int i = 0; i < LL; ++i) {
    float cfac = (float)(0.1 * (1.0 + 0.1 * (double)i));
    U2 fk0 = foldKey((uint32_t)(i * 10 + 0));
    U2 fk1 = foldKey((uint32_t)(i * 10 + 1));
    const float* attL = att + (size_t)i * HEADS * 2 * HH;

    gemm_mfma<<<GEMM_GRID, 256, 0, stream>>>(hHi, hLo,
        W0h + (size_t)i * HH * MM, W0l + (size_t)i * HH * MM, tb0 + (size_t)i * MM, Cbuf, 2);
    ln_relu_acc<<<NN, 256, 0, stream>>>(Cbuf, tg0 + (size_t)i * MM, tbe0 + (size_t)i * MM,
        feats, 1, actHi, actLo, fk0.a, fk0.b, cfac, nullptr, nullptr, nullptr, nullptr, nullptr);

    gemm_mfma<<<GEMM_GRID, 256, 0, stream>>>(actHi, actLo,
        W1h + (size_t)i * MM * MM, W1l + (size_t)i * MM * MM, tb1 + (size_t)i * MM, Cbuf, 16);
    ln_relu_acc<<<NN, 256, 0, stream>>>(Cbuf, tg1 + (size_t)i * MM, tbe1 + (size_t)i * MM,
        feats, 0, actHi, actLo, fk1.a, fk1.b, cfac, nullptr, nullptr, nullptr, nullptr, nullptr);

    gemm_mfma<<<GEMM_GRID, 256, 0, stream>>>(actHi, actLo,
        W2h + (size_t)i * MM * MM, W2l + (size_t)i * MM * MM, tb2 + (size_t)i * MM, Cbuf, 16);
    ln_relu_acc<<<NN, 256, 0, stream>>>(Cbuf, tg2 + (size_t)i * MM, tbe2 + (size_t)i * MM,
        feats, 0, nullptr, nullptr, 0u, 0u, 0.f, attL, ai, aj, featsPk8, scales);

    gat_fused<<<NN / 4, 256, 0, stream>>>(offs, csrc, ai, aj, featsPk8, scales,
        evo_W1, evo_b1, evo_W2, evo_b2, h, resid, hHi, hLo);
  }

  decoder_kernel<<<NN, 64, 0, stream>>>(resid, dsW, dsb, diW, dib, dcW, dcb, deW, deb, out);
}

// Round 22
// 1253.644 us; speedup vs baseline: 1.0347x; 1.0347x over previous
//
#include <hip/hip_runtime.h>
#include <cstdint>
#include <cstddef>

// ---------------- constants ----------------
#define NN 10000
#define EE 160000
#define F_IN 128
#define HH 64
#define HEADS 8
#define LL 6
#define MM 512
#define OUT_DIM 64
#define EPSF 1e-5f

typedef unsigned short ushort;
typedef unsigned char uchar;
typedef __attribute__((ext_vector_type(8))) short bf16x8;
typedef __attribute__((ext_vector_type(8))) unsigned short ushort8;
typedef __attribute__((ext_vector_type(4))) float f32x4;

union U8 { ushort8 u; bf16x8 b; };

// ---------------- threefry (JAX-compatible) ----------------
struct U2 { uint32_t a, b; };

__host__ __device__ constexpr uint32_t rotl32(uint32_t x, uint32_t d) {
  return (x << d) | (x >> (32u - d));
}

__host__ __device__ constexpr U2 threefry2x32(uint32_t k1, uint32_t k2, uint32_t x0, uint32_t x1) {
  uint32_t ks2 = k1 ^ k2 ^ 0x1BD11BDAu;
  x0 += k1; x1 += k2;
  x0 += x1; x1 = rotl32(x1, 13); x1 ^= x0;
  x0 += x1; x1 = rotl32(x1, 15); x1 ^= x0;
  x0 += x1; x1 = rotl32(x1, 26); x1 ^= x0;
  x0 += x1; x1 = rotl32(x1, 6);  x1 ^= x0;
  x0 += k2; x1 += ks2 + 1u;
  x0 += x1; x1 = rotl32(x1, 17); x1 ^= x0;
  x0 += x1; x1 = rotl32(x1, 29); x1 ^= x0;
  x0 += x1; x1 = rotl32(x1, 16); x1 ^= x0;
  x0 += x1; x1 = rotl32(x1, 24); x1 ^= x0;
  x0 += ks2; x1 += k1 + 2u;
  x0 += x1; x1 = rotl32(x1, 13); x1 ^= x0;
  x0 += x1; x1 = rotl32(x1, 15); x1 ^= x0;
  x0 += x1; x1 = rotl32(x1, 26); x1 ^= x0;
  x0 += x1; x1 = rotl32(x1, 6);  x1 ^= x0;
  x0 += k1; x1 += k2 + 3u;
  x0 += x1; x1 = rotl32(x1, 17); x1 ^= x0;
  x0 += x1; x1 = rotl32(x1, 29); x1 ^= x0;
  x0 += x1; x1 = rotl32(x1, 16); x1 ^= x0;
  x0 += x1; x1 = rotl32(x1, 24); x1 ^= x0;
  x0 += k2; x1 += ks2 + 4u;
  x0 += x1; x1 = rotl32(x1, 13); x1 ^= x0;
  x0 += x1; x1 = rotl32(x1, 15); x1 ^= x0;
  x0 += x1; x1 = rotl32(x1, 26); x1 ^= x0;
  x0 += x1; x1 = rotl32(x1, 6);  x1 ^= x0;
  x0 += ks2; x1 += k1 + 5u;
  return U2{x0, x1};
}

__host__ __device__ constexpr U2 foldKey(uint32_t data) {
  return threefry2x32(0u, 42u, 0u, data);
}

// XLA ErfInv f32 (Giles)
__device__ inline float erfinv_f32(float x) {
  float w = -log1pf(-x * x);
  float p;
  if (w < 5.0f) {
    w -= 2.5f;
    p = 2.81022636e-08f;
    p = fmaf(p, w, 3.43273939e-07f);
    p = fmaf(p, w, -3.5233877e-06f);
    p = fmaf(p, w, -4.39150654e-06f);
    p = fmaf(p, w, 0.00021858087f);
    p = fmaf(p, w, -0.00125372503f);
    p = fmaf(p, w, -0.00417768164f);
    p = fmaf(p, w, 0.246640727f);
    p = fmaf(p, w, 1.50140941f);
  } else {
    w = sqrtf(w) - 3.0f;
    p = -0.000200214257f;
    p = fmaf(p, w, 0.000100950558f);
    p = fmaf(p, w, 0.00134934322f);
    p = fmaf(p, w, -0.00367342844f);
    p = fmaf(p, w, 0.00573950773f);
    p = fmaf(p, w, -0.0076224613f);
    p = fmaf(p, w, 0.00943887047f);
    p = fmaf(p, w, 1.00167406f);
    p = fmaf(p, w, 2.83297682f);
  }
  return p * x;
}

__device__ inline float jax_normal(uint32_t k1, uint32_t k2, uint32_t idx) {
  U2 r = threefry2x32(k1, k2, 0u, idx);
  uint32_t bits = r.a ^ r.b;
  uint32_t fb = (bits >> 9) | 0x3f800000u;
  float f = __uint_as_float(fb) - 1.0f;
  const float lo = -0.99999994f;
  float u = f * 2.0f + lo;
  u = fmaxf(lo, u);
  return 1.41421356f * erfinv_f32(u);
}

// ---------------- helpers ----------------
__device__ inline float waveSum(float v) {
  v += __shfl_xor(v, 32, 64);
  v += __shfl_xor(v, 16, 64);
  v += __shfl_xor(v, 8, 64);
  v += __shfl_xor(v, 4, 64);
  v += __shfl_xor(v, 2, 64);
  v += __shfl_xor(v, 1, 64);
  return v;
}
__device__ inline float waveMax(float v) {
  v = fmaxf(v, __shfl_xor(v, 32, 64));
  v = fmaxf(v, __shfl_xor(v, 16, 64));
  v = fmaxf(v, __shfl_xor(v, 8, 64));
  v = fmaxf(v, __shfl_xor(v, 4, 64));
  v = fmaxf(v, __shfl_xor(v, 2, 64));
  v = fmaxf(v, __shfl_xor(v, 1, 64));
  return v;
}

__device__ inline ushort bf16rn(float x) {
  uint32_t u = __float_as_uint(x);
  uint32_t r = (u + 0x7fffu + ((u >> 16) & 1u)) >> 16;
  return (ushort)r;
}
__device__ inline float bf16tof(ushort h) {
  return __uint_as_float(((uint32_t)h) << 16);
}

// ---------------- kernels ----------------

// encoder: h = relu(LN(x @ W + b; g,be)) + cm*0.1  -> h f32 + bf16 hi/lo planes; zeroes resid
__global__ __launch_bounds__(64) void encoder_kernel(
    const float* __restrict__ x, const float* __restrict__ W, const float* __restrict__ b,
    const float* __restrict__ g, const float* __restrict__ be, const float* __restrict__ cm,
    float* __restrict__ h, ushort* __restrict__ hHi, ushort* __restrict__ hLo,
    float* __restrict__ resid) {
  __shared__ float xs[F_IN];
  int n = blockIdx.x, l = threadIdx.x;
  xs[l]      = x[(size_t)n * F_IN + l];
  xs[l + 64] = x[(size_t)n * F_IN + 64 + l];
  resid[(size_t)n * HH + l] = 0.0f;
  __syncthreads();
  float acc = b[l];
  #pragma unroll 8
  for (int k = 0; k < F_IN; k++) acc = fmaf(xs[k], W[k * HH + l], acc);
  float mu = waveSum(acc) * (1.0f / 64.0f);
  float d = acc - mu;
  float var = waveSum(d * d) * (1.0f / 64.0f);
  float y = fmaf(d / sqrtf(var + EPSF), g[l], be[l]);
  y = fmaxf(y, 0.0f);
  float hv = fmaf(cm[l], 0.1f, y);
  h[(size_t)n * HH + l] = hv;
  ushort hi = bf16rn(hv);
  size_t oi = ((size_t)(l >> 5) * NN + n) * 32 + (l & 31);
  hHi[oi] = hi;
  hLo[oi] = bf16rn(hv - bf16tof(hi));
}

// weight convert+transpose: W[K][512] f32 -> [K/32][512][32] bf16 hi/lo, per layer (z)
__global__ __launch_bounds__(256) void wconv(
    const float* __restrict__ W, ushort* __restrict__ oh, ushort* __restrict__ ol, int K) {
  __shared__ ushort Th[64][40], Tl[64][40];
  int kt = blockIdx.x;
  int m0 = blockIdx.y * 64;
  int lay = blockIdx.z;
  const float* Wl = W + (size_t)lay * K * MM;
  ushort* ohl = oh + (size_t)lay * K * MM;
  ushort* oll = ol + (size_t)lay * K * MM;
  int t = threadIdx.x;
  #pragma unroll
  for (int p = 0; p < 2; ++p) {
    int li = p * 256 + t;
    int k = li >> 4, mg = (li & 15) * 4;
    float4 v = *(const float4*)(Wl + (size_t)(kt * 32 + k) * MM + m0 + mg);
    float vv[4] = {v.x, v.y, v.z, v.w};
    #pragma unroll
    for (int q = 0; q < 4; ++q) {
      ushort hi = bf16rn(vv[q]);
      Th[mg + q][k] = hi;
      Tl[mg + q][k] = bf16rn(vv[q] - bf16tof(hi));
    }
  }
  __syncthreads();
  #pragma unroll
  for (int p = 0; p < 2; ++p) {
    int li = p * 256 + t;
    int plane = li >> 8;
    int rem = li & 255;
    int m = rem >> 2, kh = (rem & 3) * 8;
    size_t go = ((size_t)kt * MM + m0 + m) * 32 + kh;
    if (plane == 0) *(ushort8*)(ohl + go) = *(const ushort8*)&Th[m][kh];
    else            *(ushort8*)(oll + go) = *(const ushort8*)&Tl[m][kh];
  }
}

// ---- GEMM: C[NN,512] (bf16) = A @ W + bias. 128x128 tile, 512 thr (8 waves), LDS-staged.
// 8 waves share the B panel (2x B reuse vs 128x64); per-wave profile identical to R15
// (64x32 quadrant, acc[4][2], 12 ds_reads + 24 MFMA per kt). Grid 320, XCD-row-partitioned. ----
__global__ __launch_bounds__(512) void gemm_mfma(
    const ushort* __restrict__ Ahg, const ushort* __restrict__ Alg,
    const ushort* __restrict__ Whg, const ushort* __restrict__ Wlg,
    const float* __restrict__ bias, ushort* __restrict__ C, int nkt) {
  __shared__ __align__(16) ushort Ah[128][36], Al[128][36];
  __shared__ __align__(16) ushort Bh[128][36], Bl[128][36];
  int t = threadIdx.x, w = t >> 6, lane = t & 63;
  int lr = lane & 15, r4 = lane >> 4, kh = r4 * 8;
  int gid = blockIdx.x;
  int xcd = gid & 7, q = gid >> 3;          // q in [0,40)
  int lrow = q >> 2, colp = q & 3;          // 10 row-tiles x 4 col-panels per XCD
  int rowTile = xcd * 10 + lrow;
  if (rowTile >= 79) return;
  int row0 = rowTile * 128, col0 = colp * 128;
  int wr = (w & 1) * 64, wc = (w >> 1) * 32;   // 8 waves: 2 row halves x 4 col quarters
  f32x4 acc[4][2];
  #pragma unroll
  for (int i = 0; i < 4; i++)
    #pragma unroll
    for (int j = 0; j < 2; j++) acc[i][j] = (f32x4){0.f, 0.f, 0.f, 0.f};

  for (int kt = 0; kt < nkt; ++kt) {
    // stage A: 128 rows x 32 k, 2 planes; 512 ushort8 chunks, 1 per thread per plane
    {
      int r = t >> 2, kq = (t & 3) * 8;
      int n = row0 + r;
      ushort8 va = {0,0,0,0,0,0,0,0}, vl = {0,0,0,0,0,0,0,0};
      if (n < NN) {
        size_t so = ((size_t)kt * NN + n) * 32 + kq;
        va = *(const ushort8*)(Ahg + so);
        vl = *(const ushort8*)(Alg + so);
      }
      *(ushort8*)&Ah[r][kq] = va;
      *(ushort8*)&Al[r][kq] = vl;
    }
    // stage B: 128 cols x 32 k, 2 planes; 512 chunks, 1 per thread per plane
    {
      int c = t >> 2, kq = (t & 3) * 8;
      size_t so = ((size_t)kt * MM + col0 + c) * 32 + kq;
      *(ushort8*)&Bh[c][kq] = *(const ushort8*)(Whg + so);
      *(ushort8*)&Bl[c][kq] = *(const ushort8*)(Wlg + so);
    }
    __syncthreads();
    bf16x8 bh[2], bl[2];
    #pragma unroll
    for (int cf = 0; cf < 2; ++cf) {
      bh[cf] = *(const bf16x8*)&Bh[wc + cf * 16 + lr][kh];
      bl[cf] = *(const bf16x8*)&Bl[wc + cf * 16 + lr][kh];
    }
    #pragma unroll
    for (int rf = 0; rf < 4; ++rf) {
      bf16x8 ah = *(const bf16x8*)&Ah[wr + rf * 16 + lr][kh];
      bf16x8 al = *(const bf16x8*)&Al[wr + rf * 16 + lr][kh];
      #pragma unroll
      for (int cf = 0; cf < 2; ++cf) {
        acc[rf][cf] = __builtin_amdgcn_mfma_f32_16x16x32_bf16(ah, bh[cf], acc[rf][cf], 0, 0, 0);
        acc[rf][cf] = __builtin_amdgcn_mfma_f32_16x16x32_bf16(ah, bl[cf], acc[rf][cf], 0, 0, 0);
        acc[rf][cf] = __builtin_amdgcn_mfma_f32_16x16x32_bf16(al, bh[cf], acc[rf][cf], 0, 0, 0);
      }
    }
    __syncthreads();
  }
  #pragma unroll
  for (int cf = 0; cf < 2; ++cf) {
    int c = col0 + wc + cf * 16 + lr;
    float bc = bias[c];
    #pragma unroll
    for (int rf = 0; rf < 4; ++rf) {
      #pragma unroll
      for (int j = 0; j < 4; ++j) {
        int r = row0 + wr + rf * 16 + r4 * 4 + j;
        if (r < NN) C[(size_t)r * MM + c] = bf16rn(acc[rf][cf][j] + bc);
      }
    }
  }
}

// LN+relu (+feats accum, bf16) (+acts+noise pack) (+stage2: int8 featsPk + scales + GAT scores)
__global__ __launch_bounds__(256) void ln_relu_acc(
    const ushort* __restrict__ Y, const float* __restrict__ g, const float* __restrict__ be,
    ushort* __restrict__ feats, int firstDepth,
    ushort* __restrict__ outHi, ushort* __restrict__ outLo,
    uint32_t k1, uint32_t k2, float cf,
    const float* __restrict__ attL, float* __restrict__ ai, float* __restrict__ aj,
    uchar* __restrict__ featsPk8, float* __restrict__ scales) {
  int n = blockIdx.x, t = threadIdx.x;
  size_t base = (size_t)n * MM;
  float v0 = bf16tof(Y[base + t]), v1 = bf16tof(Y[base + t + 256]);
  int wid = t >> 6, lane = t & 63;
  __shared__ float red[8];
  __shared__ uchar qsh[512];
  float s = waveSum(v0 + v1);
  if (lane == 0) red[wid] = s;
  __syncthreads();
  float mu = (red[0] + red[1] + red[2] + red[3]) * (1.0f / 512.0f);
  float d0 = v0 - mu, d1 = v1 - mu;
  float q = waveSum(d0 * d0 + d1 * d1);
  if (lane == 0) red[4 + wid] = q;
  __syncthreads();
  float var = (red[4] + red[5] + red[6] + red[7]) * (1.0f / 512.0f);
  float inv = 1.0f / sqrtf(var + EPSF);
  float o0 = fmaxf(fmaf(d0 * inv, g[t], be[t]), 0.0f);
  float o1 = fmaxf(fmaf(d1 * inv, g[t + 256], be[t + 256]), 0.0f);
  float f0, f1;
  if (firstDepth) { f0 = o0; f1 = o1; }
  else { f0 = bf16tof(feats[base + t]) + o0; f1 = bf16tof(feats[base + t + 256]) + o1; }
  if (outHi) {
    feats[base + t] = bf16rn(f0); feats[base + t + 256] = bf16rn(f1);
    float y0 = fmaf(jax_normal(k1, k2, (uint32_t)(base + t)), cf, o0);
    float y1 = fmaf(jax_normal(k1, k2, (uint32_t)(base + t + 256)), cf, o1);
    int c0 = t, c1 = t + 256;
    size_t i0 = ((size_t)(c0 >> 5) * NN + n) * 32 + (c0 & 31);
    size_t i1 = ((size_t)(c1 >> 5) * NN + n) * 32 + (c1 & 31);
    ushort h0 = bf16rn(y0), h1 = bf16rn(y1);
    outHi[i0] = h0; outLo[i0] = bf16rn(y0 - bf16tof(h0));
    outHi[i1] = h1; outLo[i1] = bf16rn(y1 - bf16tof(h1));
  }
  if (attL) {
    const float inv3 = 1.0f / 3.0f;
    float w0 = f0 * inv3, w1 = f1 * inv3;
    float si0 = waveSum(w0 * attL[wid * 128 + lane]);
    float sj0 = waveSum(w0 * attL[wid * 128 + 64 + lane]);
    float si1 = waveSum(w1 * attL[(wid + 4) * 128 + lane]);
    float sj1 = waveSum(w1 * attL[(wid + 4) * 128 + 64 + lane]);
    float mx0 = waveMax(w0), mx1 = waveMax(w1);
    float r0 = (mx0 > 0.f) ? (127.0f / mx0) : 0.f;
    float r1 = (mx1 > 0.f) ? (127.0f / mx1) : 0.f;
    if (lane == 0) {
      ai[n * HEADS + wid] = si0;     aj[n * HEADS + wid] = sj0;
      ai[n * HEADS + wid + 4] = si1; aj[n * HEADS + wid + 4] = sj1;
      scales[n * HEADS + wid]     = (mx0 > 0.f) ? (mx0 * (1.0f / 127.0f)) : 0.f;
      scales[n * HEADS + wid + 4] = (mx1 > 0.f) ? (mx1 * (1.0f / 127.0f)) : 0.f;
    }
    int q0 = min(127, (int)rintf(w0 * r0));
    int q1 = min(127, (int)rintf(w1 * r1));
    qsh[lane * 8 + wid]     = (uchar)q0;
    qsh[lane * 8 + wid + 4] = (uchar)q1;
    __syncthreads();
    if (t < 32) ((uint4*)(featsPk8 + (size_t)n * 512))[t] = ((const uint4*)qsh)[t];
  }
}

// -------- CSR build --------
__global__ __launch_bounds__(256) void csr_histo(const int* __restrict__ dst, int* __restrict__ deg) {
  int e = blockIdx.x * blockDim.x + threadIdx.x;
  if (e < EE) atomicAdd(&deg[dst[e]], 1);
}

__global__ __launch_bounds__(256) void csr_scan(const int* __restrict__ deg, int* __restrict__ offs,
                                                int* __restrict__ pos) {
  __shared__ int part[256];
  int t = threadIdx.x;
  const int chunk = (NN + 255) / 256;
  int start = t * chunk;
  int s = 0;
  for (int j = 0; j < chunk; j++) { int i = start + j; if (i < NN) s += deg[i]; }
  part[t] = s; __syncthreads();
  for (int d = 1; d < 256; d <<= 1) {
    int v = (t >= d) ? part[t - d] : 0;
    __syncthreads();
    part[t] += v;
    __syncthreads();
  }
  int run = (t == 0) ? 0 : part[t - 1];
  for (int j = 0; j < chunk; j++) {
    int i = start + j;
    if (i < NN) { offs[i] = run; pos[i] = run; run += deg[i]; }
  }
  if (t == 0) offs[NN] = EE;
}

__global__ __launch_bounds__(256) void csr_fill(const int* __restrict__ src, const int* __restrict__ dst,
                                                int* __restrict__ pos, int* __restrict__ csrc) {
  int e = blockIdx.x * blockDim.x + threadIdx.x;
  if (e >= EE) return;
  int d = dst[e];
  int slot = atomicAdd(&pos[d], 1);
  csrc[slot] = src[e];
}

// -------- fused GAT v5.1: wave-per-node, zero barriers, int8 ch-major gather, 4-deep uint2 batch --------
__global__ __launch_bounds__(256) void gat_fused(
    const int* __restrict__ offs, const int* __restrict__ csrc,
    const float* __restrict__ ai, const float* __restrict__ aj,
    const uchar* __restrict__ featsPk8, const float* __restrict__ scales,
    const float* __restrict__ W1, const float* __restrict__ b1,
    const float* __restrict__ W2, const float* __restrict__ b2,
    float* __restrict__ h, float* __restrict__ resid,
    ushort* __restrict__ hHi, ushort* __restrict__ hLo) {
  __shared__ int   sSrc[4][64];
  __shared__ float sEx[4][8][64];
  __shared__ float hnSh[4][64];
  __shared__ float zSh[4][128];
  int t = threadIdx.x, wid = t >> 6, l = t & 63;
  int n = blockIdx.x * 4 + wid;
  int e0 = offs[n], e1 = offs[n + 1];
  float aiv[8];
  *(float4*)&aiv[0] = *(const float4*)&ai[(size_t)n * 8];
  *(float4*)&aiv[4] = *(const float4*)&ai[(size_t)n * 8 + 4];
  float m[8];
  #pragma unroll
  for (int q = 0; q < 8; ++q) m[q] = aiv[q] + 4.0f;

  float exAcc[8] = {0.f, 0.f, 0.f, 0.f, 0.f, 0.f, 0.f, 0.f};
  float acc[8]   = {0.f, 0.f, 0.f, 0.f, 0.f, 0.f, 0.f, 0.f};

  for (int c = e0; c < e1; c += 64) {
    int cnt = min(64, e1 - c);
    if (l < cnt) {
      int sv = csrc[c + l];
      sSrc[wid][l] = sv;
      float ajv[8], sc[8];
      *(float4*)&ajv[0] = *(const float4*)&aj[(size_t)sv * 8];
      *(float4*)&ajv[4] = *(const float4*)&aj[(size_t)sv * 8 + 4];
      *(float4*)&sc[0]  = *(const float4*)&scales[(size_t)sv * 8];
      *(float4*)&sc[4]  = *(const float4*)&scales[(size_t)sv * 8 + 4];
      #pragma unroll
      for (int q = 0; q < 8; ++q) {
        float a = aiv[q] + ajv[q];
        a = (a >= 0.f) ? a : 0.2f * a;
        float ex = expf(a - m[q]);
        exAcc[q] += ex;
        sEx[wid][q][l] = ex * sc[q];
      }
    }
    int j = 0;
    for (; j + 4 <= cnt; j += 4) {
      uint2 v0 = *(const uint2*)(featsPk8 + (size_t)sSrc[wid][j + 0] * 512 + l * 8);
      uint2 v1 = *(const uint2*)(featsPk8 + (size_t)sSrc[wid][j + 1] * 512 + l * 8);
      uint2 v2 = *(const uint2*)(featsPk8 + (size_t)sSrc[wid][j + 2] * 512 + l * 8);
      uint2 v3 = *(const uint2*)(featsPk8 + (size_t)sSrc[wid][j + 3] * 512 + l * 8);
      #pragma unroll
      for (int b = 0; b < 4; ++b) {
        uint2 v = (b == 0) ? v0 : (b == 1) ? v1 : (b == 2) ? v2 : v3;
        int jb = j + b;
        acc[0] = fmaf((float)( v.x        & 0xffu), sEx[wid][0][jb], acc[0]);
        acc[1] = fmaf((float)((v.x >>  8) & 0xffu), sEx[wid][1][jb], acc[1]);
        acc[2] = fmaf((float)((v.x >> 16) & 0xffu), sEx[wid][2][jb], acc[2]);
        acc[3] = fmaf((float)( v.x >> 24         ), sEx[wid][3][jb], acc[3]);
        acc[4] = fmaf((float)( v.y        & 0xffu), sEx[wid][4][jb], acc[4]);
        acc[5] = fmaf((float)((v.y >>  8) & 0xffu), sEx[wid][5][jb], acc[5]);
        acc[6] = fmaf((float)((v.y >> 16) & 0xffu), sEx[wid][6][jb], acc[6]);
        acc[7] = fmaf((float)( v.y >> 24         ), sEx[wid][7][jb], acc[7]);
      }
    }
    for (; j < cnt; ++j) {
      uint2 v = *(const uint2*)(featsPk8 + (size_t)sSrc[wid][j] * 512 + l * 8);
      acc[0] = fmaf((float)( v.x        & 0xffu), sEx[wid][0][j], acc[0]);
      acc[1] = fmaf((float)((v.x >>  8) & 0xffu), sEx[wid][1][j], acc[1]);
      acc[2] = fmaf((float)((v.x >> 16) & 0xffu), sEx[wid][2][j], acc[2]);
      acc[3] = fmaf((float)( v.x >> 24         ), sEx[wid][3][j], acc[3]);
      acc[4] = fmaf((float)( v.y        & 0xffu), sEx[wid][4][j], acc[4]);
      acc[5] = fmaf((float)((v.y >>  8) & 0xffu), sEx[wid][5][j], acc[5]);
      acc[6] = fmaf((float)((v.y >> 16) & 0xffu), sEx[wid][6][j], acc[6]);
      acc[7] = fmaf((float)( v.y >> 24         ), sEx[wid][7][j], acc[7]);
    }
  }
  float hsum = 0.f;
  #pragma unroll
  for (int q = 0; q < 8; ++q) {
    float d = waveSum(exAcc[q]);
    hsum += acc[q] * ((d > 0.f) ? (1.0f / d) : 0.f);
  }
  hnSh[wid][l] = hsum * 0.125f;
  float zz0 = b1[l], zz1 = b1[l + 64];
  #pragma unroll 8
  for (int k = 0; k < 64; k++) {
    float hv = hnSh[wid][k];
    zz0 = fmaf(hv, W1[k * 128 + l], zz0);
    zz1 = fmaf(hv, W1[k * 128 + 64 + l], zz1);
  }
  zSh[wid][l] = fmaxf(zz0, 0.f);
  zSh[wid][l + 64] = fmaxf(zz1, 0.f);
  float y = b2[l];
  #pragma unroll 8
  for (int k = 0; k < 128; k++) y = fmaf(zSh[wid][k], W2[k * 64 + l], y);
  float gate = 1.0f / (1.0f + expf(-tanhf(y)));
  float hp = h[(size_t)n * HH + l];
  float hb = gate * hnSh[wid][l] + (1.0f - gate) * hp;
  resid[(size_t)n * HH + l] += hb;
  float mu = waveSum(hb) * (1.0f / 64.0f);
  float dd = hb - mu;
  float var = waveSum(dd * dd) * (1.0f / 64.0f);
  float hv = dd / sqrtf(var + EPSF);
  h[(size_t)n * HH + l] = hv;
  ushort hi = bf16rn(hv);
  size_t oi = ((size_t)(l >> 5) * NN + n) * 32 + (l & 31);
  hHi[oi] = hi;
  hLo[oi] = bf16rn(hv - bf16tof(hi));
}

// decoders; out layout: state[N], imp[N], chaos[N], evo[N*64], h_multi[N*64]
__global__ __launch_bounds__(64) void decoder_kernel(
    const float* __restrict__ resid,
    const float* __restrict__ dsW, const float* __restrict__ dsb,
    const float* __restrict__ diW, const float* __restrict__ dib,
    const float* __restrict__ dcW, const float* __restrict__ dcb,
    const float* __restrict__ deW, const float* __restrict__ deb,
    float* __restrict__ out) {
  __shared__ float hm[64];
  int n = blockIdx.x, l = threadIdx.x;
  float v = resid[(size_t)n * HH + l] * (1.0f / 6.0f);
  hm[l] = v;
  float s1 = waveSum(v * dsW[l]);
  float s2 = waveSum(v * diW[l]);
  float s3 = waveSum(v * dcW[l]);
  if (l == 0) {
    out[n]          = s1 + dsb[0];
    out[NN + n]     = s2 + dib[0];
    out[2 * NN + n] = s3 + dcb[0];
  }
  __syncthreads();
  float e = deb[l];
  #pragma unroll 8
  for (int k = 0; k < 64; k++) e = fmaf(hm[k], deW[k * OUT_DIM + l], e);
  out[3 * NN + (size_t)n * OUT_DIM + l] = e;
  out[3 * NN + (size_t)NN * OUT_DIM + (size_t)n * HH + l] = v;
}

// ---------------- launch ----------------
extern "C" void kernel_launch(void* const* d_in, const int* in_sizes, int n_in,
                              void* d_out, int out_size, void* d_ws, size_t ws_size,
                              hipStream_t stream) {
  const float* x        = (const float*)d_in[0];
  const int*   ei       = (const int*)d_in[1];
  const float* enc_W    = (const float*)d_in[2];
  const float* enc_b    = (const float*)d_in[3];
  const float* enc_g    = (const float*)d_in[4];
  const float* enc_beta = (const float*)d_in[5];
  const float* cm       = (const float*)d_in[6];
  const float* tW0 = (const float*)d_in[7];  const float* tb0 = (const float*)d_in[8];
  const float* tg0 = (const float*)d_in[9];  const float* tbe0 = (const float*)d_in[10];
  const float* tW1 = (const float*)d_in[11]; const float* tb1 = (const float*)d_in[12];
  const float* tg1 = (const float*)d_in[13]; const float* tbe1 = (const float*)d_in[14];
  const float* tW2 = (const float*)d_in[15]; const float* tb2 = (const float*)d_in[16];
  const float* tg2 = (const float*)d_in[17]; const float* tbe2 = (const float*)d_in[18];
  const float* att = (const float*)d_in[19];
  const float* evo_W1 = (const float*)d_in[20]; const float* evo_b1 = (const float*)d_in[21];
  const float* evo_W2 = (const float*)d_in[22]; const float* evo_b2 = (const float*)d_in[23];
  const float* dsW = (const float*)d_in[24]; const float* dsb = (const float*)d_in[25];
  const float* diW = (const float*)d_in[26]; const float* dib = (const float*)d_in[27];
  const float* dcW = (const float*)d_in[28]; const float* dcb = (const float*)d_in[29];
  const float* deW = (const float*)d_in[30]; const float* deb = (const float*)d_in[31];
  float* out = (float*)d_out;

  const int* src = ei;
  const int* dst = ei + EE;

  float* ws = (float*)d_ws;
  size_t o = 0;
  float* h     = ws + o; o += (size_t)NN * HH;
  float* resid = ws + o; o += (size_t)NN * HH;
  float* ai    = ws + o; o += (size_t)NN * HEADS;
  float* aj    = ws + o; o += (size_t)NN * HEADS;
  float* scales = ws + o; o += (size_t)NN * HEADS;
  int* deg  = (int*)(ws + o); o += NN;
  int* offs = (int*)(ws + o); o += NN + 2;
  int* pos  = (int*)(ws + o); o += NN;
  int* csrc = (int*)(ws + o); o += EE;
  o = (o + 3) & ~(size_t)3;  // 16B align
  uchar* featsPk8 = (uchar*)(ws + o); o += (size_t)NN * 128;  // N*512 bytes
  ushort* us = (ushort*)(ws + o);
  size_t uo = 0;
  ushort* W0h = us + uo; uo += (size_t)LL * HH * MM;
  ushort* W0l = us + uo; uo += (size_t)LL * HH * MM;
  ushort* W1h = us + uo; uo += (size_t)LL * MM * MM;
  ushort* W1l = us + uo; uo += (size_t)LL * MM * MM;
  ushort* W2h = us + uo; uo += (size_t)LL * MM * MM;
  ushort* W2l = us + uo; uo += (size_t)LL * MM * MM;
  ushort* hHi = us + uo; uo += (size_t)NN * HH;
  ushort* hLo = us + uo; uo += (size_t)NN * HH;
  ushort* actHi = us + uo; uo += (size_t)NN * MM;
  ushort* actLo = us + uo; uo += (size_t)NN * MM;
  ushort* Cbuf  = us + uo; uo += (size_t)NN * MM;   // bf16 GEMM output
  ushort* feats = us + uo; uo += (size_t)NN * MM;   // bf16 feats accumulator
  (void)ws_size; (void)n_in; (void)in_sizes; (void)out_size;

  // weight conversion (deterministic each call)
  wconv<<<dim3(2, 8, 6), 256, 0, stream>>>(tW0, W0h, W0l, HH);
  wconv<<<dim3(16, 8, 6), 256, 0, stream>>>(tW1, W1h, W1l, MM);
  wconv<<<dim3(16, 8, 6), 256, 0, stream>>>(tW2, W2h, W2l, MM);

  // CSR build (csr_scan also seeds pos; no D2D memcpy)
  hipMemsetAsync(deg, 0, (size_t)NN * sizeof(int), stream);
  csr_histo<<<(EE + 255) / 256, 256, 0, stream>>>(dst, deg);
  csr_scan<<<1, 256, 0, stream>>>(deg, offs, pos);
  csr_fill<<<(EE + 255) / 256, 256, 0, stream>>>(src, dst, pos, csrc);

  encoder_kernel<<<NN, 64, 0, stream>>>(x, enc_W, enc_b, enc_g, enc_beta, cm, h, hHi, hLo, resid);

  const int GEMM_GRID = 320;  // 8 XCDs x 10 row-tiles x 4 col-panels (128-wide), row-partitioned
  for (int i = 0; i < LL; ++i) {
    float cfac = (float)(0.1 * (1.0 + 0.1 * (double)i));
    U2 fk0 = foldKey((uint32_t)(i * 10 + 0));
    U2 fk1 = foldKey((uint32_t)(i * 10 + 1));
    const float* attL = att + (size_t)i * HEADS * 2 * HH;

    gemm_mfma<<<GEMM_GRID, 512, 0, stream>>>(hHi, hLo,
        W0h + (size_t)i * HH * MM, W0l + (size_t)i * HH * MM, tb0 + (size_t)i * MM, Cbuf, 2);
    ln_relu_acc<<<NN, 256, 0, stream>>>(Cbuf, tg0 + (size_t)i * MM, tbe0 + (size_t)i * MM,
        feats, 1, actHi, actLo, fk0.a, fk0.b, cfac, nullptr, nullptr, nullptr, nullptr, nullptr);

    gemm_mfma<<<GEMM_GRID, 512, 0, stream>>>(actHi, actLo,
        W1h + (size_t)i * MM * MM, W1l + (size_t)i * MM * MM, tb1 + (size_t)i * MM, Cbuf, 16);
    ln_relu_acc<<<NN, 256, 0, stream>>>(Cbuf, tg1 + (size_t)i * MM, tbe1 + (size_t)i * MM,
        feats, 0, actHi, actLo, fk1.a, fk1.b, cfac, nullptr, nullptr, nullptr, nullptr, nullptr);

    gemm_mfma<<<GEMM_GRID, 512, 0, stream>>>(actHi, actLo,
        W2h + (size_t)i * MM * MM, W2l + (size_t)i * MM * MM, tb2 + (size_t)i * MM, Cbuf, 16);
    ln_relu_acc<<<NN, 256, 0, stream>>>(Cbuf, tg2 + (size_t)i * MM, tbe2 + (size_t)i * MM,
        feats, 0, nullptr, nullptr, 0u, 0u, 0.f, attL, ai, aj, featsPk8, scales);

    gat_fused<<<NN / 4, 256, 0, stream>>>(offs, csrc, ai, aj, featsPk8, scales,
        evo_W1, evo_b1, evo_W2, evo_b2, h, resid, hHi, hLo);
  }

  decoder_kernel<<<NN, 64, 0, stream>>>(resid, dsW, dsb, diW, dib, dcW, dcb, deW, deb, out);
}

// Round 23
// 1206.932 us; speedup vs baseline: 1.0748x; 1.0387x over previous
//
#include <hip/hip_runtime.h>
#include <cstdint>
#include <cstddef>

// ---------------- constants ----------------
#define NN 10000
#define EE 160000
#define F_IN 128
#define HH 64
#define HEADS 8
#define LL 6
#define MM 512
#define OUT_DIM 64
#define EPSF 1e-5f

typedef unsigned short ushort;
typedef unsigned char uchar;
typedef __attribute__((ext_vector_type(8))) short bf16x8;
typedef __attribute__((ext_vector_type(8))) unsigned short ushort8;
typedef __attribute__((ext_vector_type(4))) float f32x4;

union U8 { ushort8 u; bf16x8 b; };

// ---------------- threefry (JAX-compatible) ----------------
struct U2 { uint32_t a, b; };

__host__ __device__ constexpr uint32_t rotl32(uint32_t x, uint32_t d) {
  return (x << d) | (x >> (32u - d));
}

__host__ __device__ constexpr U2 threefry2x32(uint32_t k1, uint32_t k2, uint32_t x0, uint32_t x1) {
  uint32_t ks2 = k1 ^ k2 ^ 0x1BD11BDAu;
  x0 += k1; x1 += k2;
  x0 += x1; x1 = rotl32(x1, 13); x1 ^= x0;
  x0 += x1; x1 = rotl32(x1, 15); x1 ^= x0;
  x0 += x1; x1 = rotl32(x1, 26); x1 ^= x0;
  x0 += x1; x1 = rotl32(x1, 6);  x1 ^= x0;
  x0 += k2; x1 += ks2 + 1u;
  x0 += x1; x1 = rotl32(x1, 17); x1 ^= x0;
  x0 += x1; x1 = rotl32(x1, 29); x1 ^= x0;
  x0 += x1; x1 = rotl32(x1, 16); x1 ^= x0;
  x0 += x1; x1 = rotl32(x1, 24); x1 ^= x0;
  x0 += ks2; x1 += k1 + 2u;
  x0 += x1; x1 = rotl32(x1, 13); x1 ^= x0;
  x0 += x1; x1 = rotl32(x1, 15); x1 ^= x0;
  x0 += x1; x1 = rotl32(x1, 26); x1 ^= x0;
  x0 += x1; x1 = rotl32(x1, 6);  x1 ^= x0;
  x0 += k1; x1 += k2 + 3u;
  x0 += x1; x1 = rotl32(x1, 17); x1 ^= x0;
  x0 += x1; x1 = rotl32(x1, 29); x1 ^= x0;
  x0 += x1; x1 = rotl32(x1, 16); x1 ^= x0;
  x0 += x1; x1 = rotl32(x1, 24); x1 ^= x0;
  x0 += k2; x1 += ks2 + 4u;
  x0 += x1; x1 = rotl32(x1, 13); x1 ^= x0;
  x0 += x1; x1 = rotl32(x1, 15); x1 ^= x0;
  x0 += x1; x1 = rotl32(x1, 26); x1 ^= x0;
  x0 += x1; x1 = rotl32(x1, 6);  x1 ^= x0;
  x0 += ks2; x1 += k1 + 5u;
  return U2{x0, x1};
}

__host__ __device__ constexpr U2 foldKey(uint32_t data) {
  return threefry2x32(0u, 42u, 0u, data);
}

// XLA ErfInv f32 (Giles)
__device__ inline float erfinv_f32(float x) {
  float w = -log1pf(-x * x);
  float p;
  if (w < 5.0f) {
    w -= 2.5f;
    p = 2.81022636e-08f;
    p = fmaf(p, w, 3.43273939e-07f);
    p = fmaf(p, w, -3.5233877e-06f);
    p = fmaf(p, w, -4.39150654e-06f);
    p = fmaf(p, w, 0.00021858087f);
    p = fmaf(p, w, -0.00125372503f);
    p = fmaf(p, w, -0.00417768164f);
    p = fmaf(p, w, 0.246640727f);
    p = fmaf(p, w, 1.50140941f);
  } else {
    w = sqrtf(w) - 3.0f;
    p = -0.000200214257f;
    p = fmaf(p, w, 0.000100950558f);
    p = fmaf(p, w, 0.00134934322f);
    p = fmaf(p, w, -0.00367342844f);
    p = fmaf(p, w, 0.00573950773f);
    p = fmaf(p, w, -0.0076224613f);
    p = fmaf(p, w, 0.00943887047f);
    p = fmaf(p, w, 1.00167406f);
    p = fmaf(p, w, 2.83297682f);
  }
  return p * x;
}

__device__ inline float jax_normal(uint32_t k1, uint32_t k2, uint32_t idx) {
  U2 r = threefry2x32(k1, k2, 0u, idx);
  uint32_t bits = r.a ^ r.b;
  uint32_t fb = (bits >> 9) | 0x3f800000u;
  float f = __uint_as_float(fb) - 1.0f;
  const float lo = -0.99999994f;
  float u = f * 2.0f + lo;
  u = fmaxf(lo, u);
  return 1.41421356f * erfinv_f32(u);
}

// ---------------- helpers ----------------
__device__ inline float waveSum(float v) {
  v += __shfl_xor(v, 32, 64);
  v += __shfl_xor(v, 16, 64);
  v += __shfl_xor(v, 8, 64);
  v += __shfl_xor(v, 4, 64);
  v += __shfl_xor(v, 2, 64);
  v += __shfl_xor(v, 1, 64);
  return v;
}
__device__ inline float waveMax(float v) {
  v = fmaxf(v, __shfl_xor(v, 32, 64));
  v = fmaxf(v, __shfl_xor(v, 16, 64));
  v = fmaxf(v, __shfl_xor(v, 8, 64));
  v = fmaxf(v, __shfl_xor(v, 4, 64));
  v = fmaxf(v, __shfl_xor(v, 2, 64));
  v = fmaxf(v, __shfl_xor(v, 1, 64));
  return v;
}

__device__ inline ushort bf16rn(float x) {
  uint32_t u = __float_as_uint(x);
  uint32_t r = (u + 0x7fffu + ((u >> 16) & 1u)) >> 16;
  return (ushort)r;
}
__device__ inline float bf16tof(ushort h) {
  return __uint_as_float(((uint32_t)h) << 16);
}

// ---------------- kernels ----------------

// encoder: h = relu(LN(x @ W + b; g,be)) + cm*0.1  -> h f32 + bf16 hi/lo planes; zeroes resid
__global__ __launch_bounds__(64) void encoder_kernel(
    const float* __restrict__ x, const float* __restrict__ W, const float* __restrict__ b,
    const float* __restrict__ g, const float* __restrict__ be, const float* __restrict__ cm,
    float* __restrict__ h, ushort* __restrict__ hHi, ushort* __restrict__ hLo,
    float* __restrict__ resid) {
  __shared__ float xs[F_IN];
  int n = blockIdx.x, l = threadIdx.x;
  xs[l]      = x[(size_t)n * F_IN + l];
  xs[l + 64] = x[(size_t)n * F_IN + 64 + l];
  resid[(size_t)n * HH + l] = 0.0f;
  __syncthreads();
  float acc = b[l];
  #pragma unroll 8
  for (int k = 0; k < F_IN; k++) acc = fmaf(xs[k], W[k * HH + l], acc);
  float mu = waveSum(acc) * (1.0f / 64.0f);
  float d = acc - mu;
  float var = waveSum(d * d) * (1.0f / 64.0f);
  float y = fmaf(d / sqrtf(var + EPSF), g[l], be[l]);
  y = fmaxf(y, 0.0f);
  float hv = fmaf(cm[l], 0.1f, y);
  h[(size_t)n * HH + l] = hv;
  ushort hi = bf16rn(hv);
  size_t oi = ((size_t)(l >> 5) * NN + n) * 32 + (l & 31);
  hHi[oi] = hi;
  hLo[oi] = bf16rn(hv - bf16tof(hi));
}

// weight convert+transpose: W[K][512] f32 -> [K/32][512][32] bf16 hi/lo, per layer (z)
__global__ __launch_bounds__(256) void wconv(
    const float* __restrict__ W, ushort* __restrict__ oh, ushort* __restrict__ ol, int K) {
  __shared__ ushort Th[64][40], Tl[64][40];
  int kt = blockIdx.x;
  int m0 = blockIdx.y * 64;
  int lay = blockIdx.z;
  const float* Wl = W + (size_t)lay * K * MM;
  ushort* ohl = oh + (size_t)lay * K * MM;
  ushort* oll = ol + (size_t)lay * K * MM;
  int t = threadIdx.x;
  #pragma unroll
  for (int p = 0; p < 2; ++p) {
    int li = p * 256 + t;
    int k = li >> 4, mg = (li & 15) * 4;
    float4 v = *(const float4*)(Wl + (size_t)(kt * 32 + k) * MM + m0 + mg);
    float vv[4] = {v.x, v.y, v.z, v.w};
    #pragma unroll
    for (int q = 0; q < 4; ++q) {
      ushort hi = bf16rn(vv[q]);
      Th[mg + q][k] = hi;
      Tl[mg + q][k] = bf16rn(vv[q] - bf16tof(hi));
    }
  }
  __syncthreads();
  #pragma unroll
  for (int p = 0; p < 2; ++p) {
    int li = p * 256 + t;
    int plane = li >> 8;
    int rem = li & 255;
    int m = rem >> 2, kh = (rem & 3) * 8;
    size_t go = ((size_t)kt * MM + m0 + m) * 32 + kh;
    if (plane == 0) *(ushort8*)(ohl + go) = *(const ushort8*)&Th[m][kh];
    else            *(ushort8*)(oll + go) = *(const ushort8*)&Tl[m][kh];
  }
}

// ---- GEMM: C[NN,512] (bf16) = A @ W + bias. 128x128 tile, 512 thr (8 waves), LDS-staged.
// alo=1: split-bf16 A (3 MFMA); alo=0: bf16-only A (2 MFMA, half A staging).
// Weights always split. Grid 320, XCD-row-partitioned (R15/R22-verified). ----
__global__ __launch_bounds__(512) void gemm_mfma(
    const ushort* __restrict__ Ahg, const ushort* __restrict__ Alg,
    const ushort* __restrict__ Whg, const ushort* __restrict__ Wlg,
    const float* __restrict__ bias, ushort* __restrict__ C, int nkt, int alo) {
  __shared__ __align__(16) ushort Ah[128][36], Al[128][36];
  __shared__ __align__(16) ushort Bh[128][36], Bl[128][36];
  int t = threadIdx.x, w = t >> 6, lane = t & 63;
  int lr = lane & 15, r4 = lane >> 4, kh = r4 * 8;
  int gid = blockIdx.x;
  int xcd = gid & 7, q = gid >> 3;
  int lrow = q >> 2, colp = q & 3;
  int rowTile = xcd * 10 + lrow;
  if (rowTile >= 79) return;
  int row0 = rowTile * 128, col0 = colp * 128;
  int wr = (w & 1) * 64, wc = (w >> 1) * 32;
  f32x4 acc[4][2];
  #pragma unroll
  for (int i = 0; i < 4; i++)
    #pragma unroll
    for (int j = 0; j < 2; j++) acc[i][j] = (f32x4){0.f, 0.f, 0.f, 0.f};

  for (int kt = 0; kt < nkt; ++kt) {
    {
      int r = t >> 2, kq = (t & 3) * 8;
      int n = row0 + r;
      ushort8 va = {0,0,0,0,0,0,0,0};
      if (n < NN) va = *(const ushort8*)(Ahg + ((size_t)kt * NN + n) * 32 + kq);
      *(ushort8*)&Ah[r][kq] = va;
      if (alo) {
        ushort8 vl = {0,0,0,0,0,0,0,0};
        if (n < NN) vl = *(const ushort8*)(Alg + ((size_t)kt * NN + n) * 32 + kq);
        *(ushort8*)&Al[r][kq] = vl;
      }
    }
    {
      int c = t >> 2, kq = (t & 3) * 8;
      size_t so = ((size_t)kt * MM + col0 + c) * 32 + kq;
      *(ushort8*)&Bh[c][kq] = *(const ushort8*)(Whg + so);
      *(ushort8*)&Bl[c][kq] = *(const ushort8*)(Wlg + so);
    }
    __syncthreads();
    bf16x8 bh[2], bl[2];
    #pragma unroll
    for (int cf = 0; cf < 2; ++cf) {
      bh[cf] = *(const bf16x8*)&Bh[wc + cf * 16 + lr][kh];
      bl[cf] = *(const bf16x8*)&Bl[wc + cf * 16 + lr][kh];
    }
    #pragma unroll
    for (int rf = 0; rf < 4; ++rf) {
      bf16x8 ah = *(const bf16x8*)&Ah[wr + rf * 16 + lr][kh];
      #pragma unroll
      for (int cf = 0; cf < 2; ++cf) {
        acc[rf][cf] = __builtin_amdgcn_mfma_f32_16x16x32_bf16(ah, bh[cf], acc[rf][cf], 0, 0, 0);
        acc[rf][cf] = __builtin_amdgcn_mfma_f32_16x16x32_bf16(ah, bl[cf], acc[rf][cf], 0, 0, 0);
      }
      if (alo) {
        bf16x8 al = *(const bf16x8*)&Al[wr + rf * 16 + lr][kh];
        #pragma unroll
        for (int cf = 0; cf < 2; ++cf)
          acc[rf][cf] = __builtin_amdgcn_mfma_f32_16x16x32_bf16(al, bh[cf], acc[rf][cf], 0, 0, 0);
      }
    }
    __syncthreads();
  }
  #pragma unroll
  for (int cf = 0; cf < 2; ++cf) {
    int c = col0 + wc + cf * 16 + lr;
    float bc = bias[c];
    #pragma unroll
    for (int rf = 0; rf < 4; ++rf) {
      #pragma unroll
      for (int j = 0; j < 4; ++j) {
        int r = row0 + wr + rf * 16 + r4 * 4 + j;
        if (r < NN) C[(size_t)r * MM + c] = bf16rn(acc[rf][cf][j] + bc);
      }
    }
  }
}

// LN+relu (+feats accum, bf16) (+acts bf16-only +noise) (+stage2: int8 featsPk + scales + GAT scores)
__global__ __launch_bounds__(256) void ln_relu_acc(
    const ushort* __restrict__ Y, const float* __restrict__ g, const float* __restrict__ be,
    ushort* __restrict__ feats, int firstDepth,
    ushort* __restrict__ outHi,
    uint32_t k1, uint32_t k2, float cf,
    const float* __restrict__ attL, float* __restrict__ ai, float* __restrict__ aj,
    uchar* __restrict__ featsPk8, float* __restrict__ scales) {
  int n = blockIdx.x, t = threadIdx.x;
  size_t base = (size_t)n * MM;
  float v0 = bf16tof(Y[base + t]), v1 = bf16tof(Y[base + t + 256]);
  int wid = t >> 6, lane = t & 63;
  __shared__ float red[8];
  __shared__ uchar qsh[512];
  float s = waveSum(v0 + v1);
  if (lane == 0) red[wid] = s;
  __syncthreads();
  float mu = (red[0] + red[1] + red[2] + red[3]) * (1.0f / 512.0f);
  float d0 = v0 - mu, d1 = v1 - mu;
  float q = waveSum(d0 * d0 + d1 * d1);
  if (lane == 0) red[4 + wid] = q;
  __syncthreads();
  float var = (red[4] + red[5] + red[6] + red[7]) * (1.0f / 512.0f);
  float inv = 1.0f / sqrtf(var + EPSF);
  float o0 = fmaxf(fmaf(d0 * inv, g[t], be[t]), 0.0f);
  float o1 = fmaxf(fmaf(d1 * inv, g[t + 256], be[t + 256]), 0.0f);
  float f0, f1;
  if (firstDepth) { f0 = o0; f1 = o1; }
  else { f0 = bf16tof(feats[base + t]) + o0; f1 = bf16tof(feats[base + t + 256]) + o1; }
  if (outHi) {
    feats[base + t] = bf16rn(f0); feats[base + t + 256] = bf16rn(f1);
    float y0 = fmaf(jax_normal(k1, k2, (uint32_t)(base + t)), cf, o0);
    float y1 = fmaf(jax_normal(k1, k2, (uint32_t)(base + t + 256)), cf, o1);
    int c0 = t, c1 = t + 256;
    size_t i0 = ((size_t)(c0 >> 5) * NN + n) * 32 + (c0 & 31);
    size_t i1 = ((size_t)(c1 >> 5) * NN + n) * 32 + (c1 & 31);
    outHi[i0] = bf16rn(y0);
    outHi[i1] = bf16rn(y1);
  }
  if (attL) {
    const float inv3 = 1.0f / 3.0f;
    float w0 = f0 * inv3, w1 = f1 * inv3;
    float si0 = waveSum(w0 * attL[wid * 128 + lane]);
    float sj0 = waveSum(w0 * attL[wid * 128 + 64 + lane]);
    float si1 = waveSum(w1 * attL[(wid + 4) * 128 + lane]);
    float sj1 = waveSum(w1 * attL[(wid + 4) * 128 + 64 + lane]);
    float mx0 = waveMax(w0), mx1 = waveMax(w1);
    float r0 = (mx0 > 0.f) ? (127.0f / mx0) : 0.f;
    float r1 = (mx1 > 0.f) ? (127.0f / mx1) : 0.f;
    if (lane == 0) {
      ai[n * HEADS + wid] = si0;     aj[n * HEADS + wid] = sj0;
      ai[n * HEADS + wid + 4] = si1; aj[n * HEADS + wid + 4] = sj1;
      scales[n * HEADS + wid]     = (mx0 > 0.f) ? (mx0 * (1.0f / 127.0f)) : 0.f;
      scales[n * HEADS + wid + 4] = (mx1 > 0.f) ? (mx1 * (1.0f / 127.0f)) : 0.f;
    }
    int q0 = min(127, (int)rintf(w0 * r0));
    int q1 = min(127, (int)rintf(w1 * r1));
    qsh[lane * 8 + wid]     = (uchar)q0;
    qsh[lane * 8 + wid + 4] = (uchar)q1;
    __syncthreads();
    if (t < 32) ((uint4*)(featsPk8 + (size_t)n * 512))[t] = ((const uint4*)qsh)[t];
  }
}

// -------- CSR build --------
__global__ __launch_bounds__(256) void csr_histo(const int* __restrict__ dst, int* __restrict__ deg) {
  int e = blockIdx.x * blockDim.x + threadIdx.x;
  if (e < EE) atomicAdd(&deg[dst[e]], 1);
}

__global__ __launch_bounds__(256) void csr_scan(const int* __restrict__ deg, int* __restrict__ offs,
                                                int* __restrict__ pos) {
  __shared__ int part[256];
  int t = threadIdx.x;
  const int chunk = (NN + 255) / 256;
  int start = t * chunk;
  int s = 0;
  for (int j = 0; j < chunk; j++) { int i = start + j; if (i < NN) s += deg[i]; }
  part[t] = s; __syncthreads();
  for (int d = 1; d < 256; d <<= 1) {
    int v = (t >= d) ? part[t - d] : 0;
    __syncthreads();
    part[t] += v;
    __syncthreads();
  }
  int run = (t == 0) ? 0 : part[t - 1];
  for (int j = 0; j < chunk; j++) {
    int i = start + j;
    if (i < NN) { offs[i] = run; pos[i] = run; run += deg[i]; }
  }
  if (t == 0) offs[NN] = EE;
}

__global__ __launch_bounds__(256) void csr_fill(const int* __restrict__ src, const int* __restrict__ dst,
                                                int* __restrict__ pos, int* __restrict__ csrc) {
  int e = blockIdx.x * blockDim.x + threadIdx.x;
  if (e >= EE) return;
  int d = dst[e];
  int slot = atomicAdd(&pos[d], 1);
  csrc[slot] = src[e];
}

// -------- fused GAT v5.1: wave-per-node, zero barriers, int8 ch-major gather, 4-deep uint2 batch --------
__global__ __launch_bounds__(256) void gat_fused(
    const int* __restrict__ offs, const int* __restrict__ csrc,
    const float* __restrict__ ai, const float* __restrict__ aj,
    const uchar* __restrict__ featsPk8, const float* __restrict__ scales,
    const float* __restrict__ W1, const float* __restrict__ b1,
    const float* __restrict__ W2, const float* __restrict__ b2,
    float* __restrict__ h, float* __restrict__ resid,
    ushort* __restrict__ hHi, ushort* __restrict__ hLo) {
  __shared__ int   sSrc[4][64];
  __shared__ float sEx[4][8][64];
  __shared__ float hnSh[4][64];
  __shared__ float zSh[4][128];
  int t = threadIdx.x, wid = t >> 6, l = t & 63;
  int n = blockIdx.x * 4 + wid;
  int e0 = offs[n], e1 = offs[n + 1];
  float aiv[8];
  *(float4*)&aiv[0] = *(const float4*)&ai[(size_t)n * 8];
  *(float4*)&aiv[4] = *(const float4*)&ai[(size_t)n * 8 + 4];
  float m[8];
  #pragma unroll
  for (int q = 0; q < 8; ++q) m[q] = aiv[q] + 4.0f;

  float exAcc[8] = {0.f, 0.f, 0.f, 0.f, 0.f, 0.f, 0.f, 0.f};
  float acc[8]   = {0.f, 0.f, 0.f, 0.f, 0.f, 0.f, 0.f, 0.f};

  for (int c = e0; c < e1; c += 64) {
    int cnt = min(64, e1 - c);
    if (l < cnt) {
      int sv = csrc[c + l];
      sSrc[wid][l] = sv;
      float ajv[8], sc[8];
      *(float4*)&ajv[0] = *(const float4*)&aj[(size_t)sv * 8];
      *(float4*)&ajv[4] = *(const float4*)&aj[(size_t)sv * 8 + 4];
      *(float4*)&sc[0]  = *(const float4*)&scales[(size_t)sv * 8];
      *(float4*)&sc[4]  = *(const float4*)&scales[(size_t)sv * 8 + 4];
      #pragma unroll
      for (int q = 0; q < 8; ++q) {
        float a = aiv[q] + ajv[q];
        a = (a >= 0.f) ? a : 0.2f * a;
        float ex = expf(a - m[q]);
        exAcc[q] += ex;
        sEx[wid][q][l] = ex * sc[q];
      }
    }
    int j = 0;
    for (; j + 4 <= cnt; j += 4) {
      uint2 v0 = *(const uint2*)(featsPk8 + (size_t)sSrc[wid][j + 0] * 512 + l * 8);
      uint2 v1 = *(const uint2*)(featsPk8 + (size_t)sSrc[wid][j + 1] * 512 + l * 8);
      uint2 v2 = *(const uint2*)(featsPk8 + (size_t)sSrc[wid][j + 2] * 512 + l * 8);
      uint2 v3 = *(const uint2*)(featsPk8 + (size_t)sSrc[wid][j + 3] * 512 + l * 8);
      #pragma unroll
      for (int b = 0; b < 4; ++b) {
        uint2 v = (b == 0) ? v0 : (b == 1) ? v1 : (b == 2) ? v2 : v3;
        int jb = j + b;
        acc[0] = fmaf((float)( v.x        & 0xffu), sEx[wid][0][jb], acc[0]);
        acc[1] = fmaf((float)((v.x >>  8) & 0xffu), sEx[wid][1][jb], acc[1]);
        acc[2] = fmaf((float)((v.x >> 16) & 0xffu), sEx[wid][2][jb], acc[2]);
        acc[3] = fmaf((float)( v.x >> 24         ), sEx[wid][3][jb], acc[3]);
        acc[4] = fmaf((float)( v.y        & 0xffu), sEx[wid][4][jb], acc[4]);
        acc[5] = fmaf((float)((v.y >>  8) & 0xffu), sEx[wid][5][jb], acc[5]);
        acc[6] = fmaf((float)((v.y >> 16) & 0xffu), sEx[wid][6][jb], acc[6]);
        acc[7] = fmaf((float)( v.y >> 24         ), sEx[wid][7][jb], acc[7]);
      }
    }
    for (; j < cnt; ++j) {
      uint2 v = *(const uint2*)(featsPk8 + (size_t)sSrc[wid][j] * 512 + l * 8);
      acc[0] = fmaf((float)( v.x        & 0xffu), sEx[wid][0][j], acc[0]);
      acc[1] = fmaf((float)((v.x >>  8) & 0xffu), sEx[wid][1][j], acc[1]);
      acc[2] = fmaf((float)((v.x >> 16) & 0xffu), sEx[wid][2][j], acc[2]);
      acc[3] = fmaf((float)( v.x >> 24         ), sEx[wid][3][j], acc[3]);
      acc[4] = fmaf((float)( v.y        & 0xffu), sEx[wid][4][j], acc[4]);
      acc[5] = fmaf((float)((v.y >>  8) & 0xffu), sEx[wid][5][j], acc[5]);
      acc[6] = fmaf((float)((v.y >> 16) & 0xffu), sEx[wid][6][j], acc[6]);
      acc[7] = fmaf((float)( v.y >> 24         ), sEx[wid][7][j], acc[7]);
    }
  }
  float hsum = 0.f;
  #pragma unroll
  for (int q = 0; q < 8; ++q) {
    float d = waveSum(exAcc[q]);
    hsum += acc[q] * ((d > 0.f) ? (1.0f / d) : 0.f);
  }
  hnSh[wid][l] = hsum * 0.125f;
  float zz0 = b1[l], zz1 = b1[l + 64];
  #pragma unroll 8
  for (int k = 0; k < 64; k++) {
    float hv = hnSh[wid][k];
    zz0 = fmaf(hv, W1[k * 128 + l], zz0);
    zz1 = fmaf(hv, W1[k * 128 + 64 + l], zz1);
  }
  zSh[wid][l] = fmaxf(zz0, 0.f);
  zSh[wid][l + 64] = fmaxf(zz1, 0.f);
  float y = b2[l];
  #pragma unroll 8
  for (int k = 0; k < 128; k++) y = fmaf(zSh[wid][k], W2[k * 64 + l], y);
  float gate = 1.0f / (1.0f + expf(-tanhf(y)));
  float hp = h[(size_t)n * HH + l];
  float hb = gate * hnSh[wid][l] + (1.0f - gate) * hp;
  resid[(size_t)n * HH + l] += hb;
  float mu = waveSum(hb) * (1.0f / 64.0f);
  float dd = hb - mu;
  float var = waveSum(dd * dd) * (1.0f / 64.0f);
  float hv = dd / sqrtf(var + EPSF);
  h[(size_t)n * HH + l] = hv;
  ushort hi = bf16rn(hv);
  size_t oi = ((size_t)(l >> 5) * NN + n) * 32 + (l & 31);
  hHi[oi] = hi;
  hLo[oi] = bf16rn(hv - bf16tof(hi));
}

// decoders; out layout: state[N], imp[N], chaos[N], evo[N*64], h_multi[N*64]
__global__ __launch_bounds__(64) void decoder_kernel(
    const float* __restrict__ resid,
    const float* __restrict__ dsW, const float* __restrict__ dsb,
    const float* __restrict__ diW, const float* __restrict__ dib,
    const float* __restrict__ dcW, const float* __restrict__ dcb,
    const float* __restrict__ deW, const float* __restrict__ deb,
    float* __restrict__ out) {
  __shared__ float hm[64];
  int n = blockIdx.x, l = threadIdx.x;
  float v = resid[(size_t)n * HH + l] * (1.0f / 6.0f);
  hm[l] = v;
  float s1 = waveSum(v * dsW[l]);
  float s2 = waveSum(v * diW[l]);
  float s3 = waveSum(v * dcW[l]);
  if (l == 0) {
    out[n]          = s1 + dsb[0];
    out[NN + n]     = s2 + dib[0];
    out[2 * NN + n] = s3 + dcb[0];
  }
  __syncthreads();
  float e = deb[l];
  #pragma unroll 8
  for (int k = 0; k < 64; k++) e = fmaf(hm[k], deW[k * OUT_DIM + l], e);
  out[3 * NN + (size_t)n * OUT_DIM + l] = e;
  out[3 * NN + (size_t)NN * OUT_DIM + (size_t)n * HH + l] = v;
}

// ---------------- launch ----------------
extern "C" void kernel_launch(void* const* d_in, const int* in_sizes, int n_in,
                              void* d_out, int out_size, void* d_ws, size_t ws_size,
                              hipStream_t stream) {
  const float* x        = (const float*)d_in[0];
  const int*   ei       = (const int*)d_in[1];
  const float* enc_W    = (const float*)d_in[2];
  const float* enc_b    = (const float*)d_in[3];
  const float* enc_g    = (const float*)d_in[4];
  const float* enc_beta = (const float*)d_in[5];
  const float* cm       = (const float*)d_in[6];
  const float* tW0 = (const float*)d_in[7];  const float* tb0 = (const float*)d_in[8];
  const float* tg0 = (const float*)d_in[9];  const float* tbe0 = (const float*)d_in[10];
  const float* tW1 = (const float*)d_in[11]; const float* tb1 = (const float*)d_in[12];
  const float* tg1 = (const float*)d_in[13]; const float* tbe1 = (const float*)d_in[14];
  const float* tW2 = (const float*)d_in[15]; const float* tb2 = (const float*)d_in[16];
  const float* tg2 = (const float*)d_in[17]; const float* tbe2 = (const float*)d_in[18];
  const float* att = (const float*)d_in[19];
  const float* evo_W1 = (const float*)d_in[20]; const float* evo_b1 = (const float*)d_in[21];
  const float* evo_W2 = (const float*)d_in[22]; const float* evo_b2 = (const float*)d_in[23];
  const float* dsW = (const float*)d_in[24]; const float* dsb = (const float*)d_in[25];
  const float* diW = (const float*)d_in[26]; const float* dib = (const float*)d_in[27];
  const float* dcW = (const float*)d_in[28]; const float* dcb = (const float*)d_in[29];
  const float* deW = (const float*)d_in[30]; const float* deb = (const float*)d_in[31];
  float* out = (float*)d_out;

  const int* src = ei;
  const int* dst = ei + EE;

  float* ws = (float*)d_ws;
  size_t o = 0;
  float* h     = ws + o; o += (size_t)NN * HH;
  float* resid = ws + o; o += (size_t)NN * HH;
  float* ai    = ws + o; o += (size_t)NN * HEADS;
  float* aj    = ws + o; o += (size_t)NN * HEADS;
  float* scales = ws + o; o += (size_t)NN * HEADS;
  int* deg  = (int*)(ws + o); o += NN;
  int* offs = (int*)(ws + o); o += NN + 2;
  int* pos  = (int*)(ws + o); o += NN;
  int* csrc = (int*)(ws + o); o += EE;
  o = (o + 3) & ~(size_t)3;  // 16B align
  uchar* featsPk8 = (uchar*)(ws + o); o += (size_t)NN * 128;  // N*512 bytes
  ushort* us = (ushort*)(ws + o);
  size_t uo = 0;
  ushort* W0h = us + uo; uo += (size_t)LL * HH * MM;
  ushort* W0l = us + uo; uo += (size_t)LL * HH * MM;
  ushort* W1h = us + uo; uo += (size_t)LL * MM * MM;
  ushort* W1l = us + uo; uo += (size_t)LL * MM * MM;
  ushort* W2h = us + uo; uo += (size_t)LL * MM * MM;
  ushort* W2l = us + uo; uo += (size_t)LL * MM * MM;
  ushort* hHi = us + uo; uo += (size_t)NN * HH;
  ushort* hLo = us + uo; uo += (size_t)NN * HH;
  ushort* actHi = us + uo; uo += (size_t)NN * MM;
  ushort* Cbuf  = us + uo; uo += (size_t)NN * MM;   // bf16 GEMM output
  ushort* feats = us + uo; uo += (size_t)NN * MM;   // bf16 feats accumulator
  (void)ws_size; (void)n_in; (void)in_sizes; (void)out_size;

  // weight conversion (deterministic each call)
  wconv<<<dim3(2, 8, 6), 256, 0, stream>>>(tW0, W0h, W0l, HH);
  wconv<<<dim3(16, 8, 6), 256, 0, stream>>>(tW1, W1h, W1l, MM);
  wconv<<<dim3(16, 8, 6), 256, 0, stream>>>(tW2, W2h, W2l, MM);

  // CSR build (csr_scan also seeds pos; no D2D memcpy)
  hipMemsetAsync(deg, 0, (size_t)NN * sizeof(int), stream);
  csr_histo<<<(EE + 255) / 256, 256, 0, stream>>>(dst, deg);
  csr_scan<<<1, 256, 0, stream>>>(deg, offs, pos);
  csr_fill<<<(EE + 255) / 256, 256, 0, stream>>>(src, dst, pos, csrc);

  encoder_kernel<<<NN, 64, 0, stream>>>(x, enc_W, enc_b, enc_g, enc_beta, cm, h, hHi, hLo, resid);

  const int GEMM_GRID = 320;  // 8 XCDs x 10 row-tiles x 4 col-panels (128-wide), row-partitioned
  for (int i = 0; i < LL; ++i) {
    float cfac = (float)(0.1 * (1.0 + 0.1 * (double)i));
    U2 fk0 = foldKey((uint32_t)(i * 10 + 0));
    U2 fk1 = foldKey((uint32_t)(i * 10 + 1));
    const float* attL = att + (size_t)i * HEADS * 2 * HH;

    // stage 0: split-A (h is the precision-critical recurrent state), K=64
    gemm_mfma<<<GEMM_GRID, 512, 0, stream>>>(hHi, hLo,
        W0h + (size_t)i * HH * MM, W0l + (size_t)i * HH * MM, tb0 + (size_t)i * MM, Cbuf, 2, 1);
    ln_relu_acc<<<NN, 256, 0, stream>>>(Cbuf, tg0 + (size_t)i * MM, tbe0 + (size_t)i * MM,
        feats, 1, actHi, fk0.a, fk0.b, cfac, nullptr, nullptr, nullptr, nullptr, nullptr);

    // stages 1-2: bf16-only A (2 MFMA/kt, half A staging)
    gemm_mfma<<<GEMM_GRID, 512, 0, stream>>>(actHi, nullptr,
        W1h + (size_t)i * MM * MM, W1l + (size_t)i * MM * MM, tb1 + (size_t)i * MM, Cbuf, 16, 0);
    ln_relu_acc<<<NN, 256, 0, stream>>>(Cbuf, tg1 + (size_t)i * MM, tbe1 + (size_t)i * MM,
        feats, 0, actHi, fk1.a, fk1.b, cfac, nullptr, nullptr, nullptr, nullptr, nullptr);

    gemm_mfma<<<GEMM_GRID, 512, 0, stream>>>(actHi, nullptr,
        W2h + (size_t)i * MM * MM, W2l + (size_t)i * MM * MM, tb2 + (size_t)i * MM, Cbuf, 16, 0);
    ln_relu_acc<<<NN, 256, 0, stream>>>(Cbuf, tg2 + (size_t)i * MM, tbe2 + (size_t)i * MM,
        feats, 0, nullptr, 0u, 0u, 0.f, attL, ai, aj, featsPk8, scales);

    gat_fused<<<NN / 4, 256, 0, stream>>>(offs, csrc, ai, aj, featsPk8, scales,
        evo_W1, evo_b1, evo_W2, evo_b2, h, resid, hHi, hLo);
  }

  decoder_kernel<<<NN, 64, 0, stream>>>(resid, dsW, dsb, diW, dib, dcW, dcb, deW, deb, out);
}